// Round 2
// baseline (478.404 us; speedup 1.0000x reference)
//
#include <hip/hip_runtime.h>
#include <math.h>

// AdaptiveGraphAttention — MI355X f32 implementation, round 2.
// Algebraic reductions vs reference:
//  * edge_attr @ w_edge1 decomposed as P[i] + Q[j]  (rank structure of concat(de_i, de_j))
//  * w_edge2 folded with w_attn[2HD:] into W2eff (512x8): per-pair cost = LN + 512x8 dot
//  * only j>=1 edge scores computed (column 0 always masked; softmax 0 matches ref exactly)
//  * hard - stop_grad(gt) + gt == hard bit-exactly (Sterbenz); sigmoid(x)>0.5 <=> x>0
// Round-2 structural change: multi-job GEMM on blockIdx.z — {de,q,k,v} one dispatch,
// {P,Q} one dispatch; 12 -> 8 total dispatches, >2 blocks/CU on the big GEMM.

constexpr int kD  = 512;
constexpr int kH  = 8;
constexpr int kHD = 64;
constexpr int kB  = 16;
constexpr int kN  = 64;
constexpr int kS  = 65;

__device__ __forceinline__ float wsum(float x) {
#pragma unroll
  for (int m = 1; m < 64; m <<= 1) x += __shfl_xor(x, m, 64);
  return x;
}
__device__ __forceinline__ float wmax(float x) {
#pragma unroll
  for (int m = 1; m < 64; m <<= 1) x = fmaxf(x, __shfl_xor(x, m, 64));
  return x;
}

// ---------------------------------------------------------------- GEMM (f32)
// C[M,N] = A[M,K] @ W[K,N] + bias[N]  (row-major; bias may be null).
// BM=BN=64, BK=32, 256 threads, 4x4 micro-tile. Up to 4 independent jobs
// selected by blockIdx.z (packs small GEMMs into one dispatch for occupancy).
#define BM 64
#define BN 64
#define BK 32

struct GJob { const float* A; const float* W; const float* bias; float* C; int M; };
struct GJobs { GJob j[4]; };

__global__ __launch_bounds__(256) void gemm_multi(GJobs jobs, int N, int K)
{
  const GJob jb = jobs.j[blockIdx.z];
  const float* __restrict__ A = jb.A;
  const float* __restrict__ W = jb.W;
  const float* __restrict__ bias = jb.bias;
  float* __restrict__ C = jb.C;
  const int M = jb.M;

  __shared__ float Ast[BK][BM + 1];  // [kk][r], padded
  __shared__ float Bs[BK][BN];
  const int bm = blockIdx.x * BM, bn = blockIdx.y * BN;
  const int tid = threadIdx.x;
  const int tx = tid & 15, ty = tid >> 4;
  float acc[4][4] = {};

  for (int k0 = 0; k0 < K; k0 += BK) {
    {
      const int kk = tid & 31, r0 = tid >> 5;      // A: 64x32 tile
#pragma unroll
      for (int it = 0; it < 8; ++it) {
        const int r = r0 + it * 8;
        const int row = bm + r;
        Ast[kk][r] = (row < M) ? A[(size_t)row * K + k0 + kk] : 0.f;
      }
      const int n = tid & 63, kr0 = tid >> 6;      // B: 32x64 tile
#pragma unroll
      for (int it = 0; it < 8; ++it) {
        const int kr = kr0 + it * 4;
        Bs[kr][n] = W[(size_t)(k0 + kr) * N + bn + n];
      }
    }
    __syncthreads();
#pragma unroll
    for (int kk = 0; kk < BK; ++kk) {
      const float a0 = Ast[kk][ty * 4 + 0];
      const float a1 = Ast[kk][ty * 4 + 1];
      const float a2 = Ast[kk][ty * 4 + 2];
      const float a3 = Ast[kk][ty * 4 + 3];
      const float4 bv = *reinterpret_cast<const float4*>(&Bs[kk][tx * 4]);
      acc[0][0] += a0 * bv.x; acc[0][1] += a0 * bv.y; acc[0][2] += a0 * bv.z; acc[0][3] += a0 * bv.w;
      acc[1][0] += a1 * bv.x; acc[1][1] += a1 * bv.y; acc[1][2] += a1 * bv.z; acc[1][3] += a1 * bv.w;
      acc[2][0] += a2 * bv.x; acc[2][1] += a2 * bv.y; acc[2][2] += a2 * bv.z; acc[2][3] += a2 * bv.w;
      acc[3][0] += a3 * bv.x; acc[3][1] += a3 * bv.y; acc[3][2] += a3 * bv.z; acc[3][3] += a3 * bv.w;
    }
    __syncthreads();
  }
#pragma unroll
  for (int i = 0; i < 4; ++i) {
    const int row = bm + ty * 4 + i;
    if (row < M) {
#pragma unroll
      for (int j = 0; j < 4; ++j) {
        const int col = bn + tx * 4 + j;
        const float b = bias ? bias[col] : 0.f;
        C[(size_t)row * N + col] = acc[i][j] + b;
      }
    }
  }
}

// -------------------------------------------------- fold w_edge2 with we_a
// w2eff[c,h] = sum_d w_edge2[c, h*64+d] * w_attn[128+d];  b2eff likewise.
__global__ void prep_w2eff(const float* __restrict__ w_edge2,
                           const float* __restrict__ b_edge2,
                           const float* __restrict__ w_attn,
                           float* __restrict__ w2eff, float* __restrict__ b2eff)
{
  const int c = blockIdx.x;          // 0..512 (512 => bias row)
  const int lane = threadIdx.x;      // 64
  const float wa = w_attn[2 * kHD + lane];
  if (c < kD) {
#pragma unroll
    for (int h = 0; h < kH; ++h) {
      const float s = wsum(w_edge2[(size_t)c * kD + h * kHD + lane] * wa);
      if (lane == 0) w2eff[c * kH + h] = s;
    }
  } else {
#pragma unroll
    for (int h = 0; h < kH; ++h) {
      const float s = wsum(b_edge2[h * kHD + lane] * wa);
      if (lane == 0) b2eff[h] = s;
    }
  }
}

// ------------------------------------------------------- row inverse norms
// wave per row: first B*N rows of de, then B*N rows of nv[:,1:,:]
__global__ __launch_bounds__(256) void norms_kernel(
    const float* __restrict__ de, const float* __restrict__ nv,
    float* __restrict__ invde, float* __restrict__ invvar)
{
  const int wid = blockIdx.x * 4 + (threadIdx.x >> 6);
  const int lane = threadIdx.x & 63;
  const float* row;
  if (wid < kB * kN) {
    row = de + (size_t)wid * kD;
  } else {
    const int t = wid - kB * kN;
    row = nv + ((size_t)(t / kN) * kS + 1 + (t % kN)) * kD;
  }
  const float4* r4 = reinterpret_cast<const float4*>(row) + lane * 2;
  const float4 x0 = r4[0], x1 = r4[1];
  float ss = x0.x * x0.x + x0.y * x0.y + x0.z * x0.z + x0.w * x0.w
           + x1.x * x1.x + x1.y * x1.y + x1.z * x1.z + x1.w * x1.w;
  ss = wsum(ss);
  if (lane == 0) {
    const float inv = 1.f / sqrtf(ss);
    if (wid < kB * kN) invde[wid] = inv; else invvar[wid - kB * kN] = inv;
  }
}

__device__ __forceinline__ float dot8(const float4 a0, const float4 a1,
                                      const float4 b0, const float4 b1)
{
  return a0.x * b0.x + a0.y * b0.y + a0.z * b0.z + a0.w * b0.w
       + a1.x * b1.x + a1.y * b1.y + a1.z * b1.z + a1.w * b1.w;
}

// ---------------------------------------------------------- adjacency rows
// block per (b,i): hard-threshold cosine sim of de, softmax(hard * cos(var))
__global__ __launch_bounds__(256) void adjacency_kernel(
    const float* __restrict__ de, const float* __restrict__ nv,
    const float* __restrict__ invde, const float* __restrict__ invvar,
    const float* __restrict__ topo_p, float* __restrict__ adj)
{
  __shared__ float lg[kN];
  const int b = blockIdx.x >> 6, i = blockIdx.x & 63;
  const int w = threadIdx.x >> 6, lane = threadIdx.x & 63;
  const float topo = topo_p[0];
  const float4* di = reinterpret_cast<const float4*>(de + ((size_t)b * kN + i) * kD) + lane * 2;
  const float4* vi = reinterpret_cast<const float4*>(nv + ((size_t)b * kS + 1 + i) * kD) + lane * 2;
  const float4 di0 = di[0], di1 = di[1];
  const float4 vi0 = vi[0], vi1 = vi[1];
  const float inv_i_d = invde[b * kN + i];
  const float inv_i_v = invvar[b * kN + i];
#pragma unroll 4
  for (int jj = 0; jj < 16; ++jj) {
    const int j = w * 16 + jj;
    const float4* dj = reinterpret_cast<const float4*>(de + ((size_t)b * kN + j) * kD) + lane * 2;
    float g = dot8(di0, di1, dj[0], dj[1]);
    g = wsum(g);
    const float4* vj = reinterpret_cast<const float4*>(nv + ((size_t)b * kS + 1 + j) * kD) + lane * 2;
    float sv = dot8(vi0, vi1, vj[0], vj[1]);
    sv = wsum(sv);
    if (lane == 0) {
      const float gs = g * inv_i_d * invde[b * kN + j] + topo;
      const bool hard = (gs > 0.f) && (j != i);      // sigmoid(x)>0.5 <=> x>0
      lg[j] = hard ? sv * inv_i_v * invvar[b * kN + j] : 0.f;
    }
  }
  __syncthreads();
  if (threadIdx.x < 64) {
    const float x = lg[lane];
    const float m = wmax(x);
    const float e = expf(x - m);
    const float s = wsum(e);
    adj[((size_t)b * kN + i) * kN + lane] = e / s;
  }
}

// --------------------------------------------------------- q/k attn scores
// thread per (which,b,s,h): dot(row_head, w_attn_part)
__global__ __launch_bounds__(256) void qk_scores(
    const float* __restrict__ q, const float* __restrict__ k,
    const float* __restrict__ w_attn,
    float* __restrict__ sq, float* __restrict__ sk)
{
  const int t = blockIdx.x * 256 + threadIdx.x;   // 0 .. 2*B*S*H-1
  const int total = kB * kS * kH;
  const int which = (t >= total) ? 1 : 0;
  const int r = which ? t - total : t;
  const int h = r % kH, bs = r / kH;
  const float* src = which ? k : q;
  const float* wa = w_attn + which * kHD;
  const float4* row = reinterpret_cast<const float4*>(src + (size_t)bs * kD + h * kHD);
  const float4* w4 = reinterpret_cast<const float4*>(wa);
  float acc = 0.f;
#pragma unroll
  for (int c = 0; c < kHD / 4; ++c) {
    const float4 a = row[c], w = w4[c];
    acc += a.x * w.x + a.y * w.y + a.z * w.z + a.w * w.w;
  }
  (which ? sk : sq)[r] = acc;
}

// -------------------------------------------------------------- edge scores
// wave per pair (b, i in [0,S), j-1 in [0,N)):  z = P[.] + Q[.], LN, relu,
// 8-head dot with W2eff.  es layout (B,S,S,H), only j>=1 written.
__global__ __launch_bounds__(256) void edge_scores(
    const float* __restrict__ Pp, const float* __restrict__ Qq,
    const float* __restrict__ gamma, const float* __restrict__ beta,
    const float* __restrict__ w2eff, const float* __restrict__ b2eff,
    float* __restrict__ es)
{
  const int wid = blockIdx.x * 4 + (threadIdx.x >> 6);
  const int lane = threadIdx.x & 63;
  const int b = wid / (kS * kN);
  const int r = wid % (kS * kN);
  const int i = r / kN, jj = r % kN;                 // j = jj+1
  const int prow = b * kN + (i == 0 ? jj : i - 1);
  const int qrow = b * kN + jj;
  const float4* p4 = reinterpret_cast<const float4*>(Pp + (size_t)prow * kD) + lane * 2;
  const float4* q4 = reinterpret_cast<const float4*>(Qq + (size_t)qrow * kD) + lane * 2;
  const float4 p0 = p4[0], p1 = p4[1], q0 = q4[0], q1 = q4[1];
  float z[8] = { p0.x + q0.x, p0.y + q0.y, p0.z + q0.z, p0.w + q0.w,
                 p1.x + q1.x, p1.y + q1.y, p1.z + q1.z, p1.w + q1.w };
  float s1 = ((z[0] + z[1]) + (z[2] + z[3])) + ((z[4] + z[5]) + (z[6] + z[7]));
  float s2 = ((z[0]*z[0] + z[1]*z[1]) + (z[2]*z[2] + z[3]*z[3]))
           + ((z[4]*z[4] + z[5]*z[5]) + (z[6]*z[6] + z[7]*z[7]));
  s1 = wsum(s1);
  s2 = wsum(s2);
  const float mu = s1 * (1.f / kD);
  const float var = s2 * (1.f / kD) - mu * mu;
  const float rstd = rsqrtf(var + 1e-5f);
  const int c0 = lane * 8;
  const float4* g4 = reinterpret_cast<const float4*>(gamma + c0);
  const float4* be4 = reinterpret_cast<const float4*>(beta + c0);
  const float4 ga = g4[0], gb = g4[1], ba = be4[0], bb = be4[1];
  const float gv[8] = { ga.x, ga.y, ga.z, ga.w, gb.x, gb.y, gb.z, gb.w };
  const float bv[8] = { ba.x, ba.y, ba.z, ba.w, bb.x, bb.y, bb.z, bb.w };
  float acc[8] = {};
#pragma unroll
  for (int t = 0; t < 8; ++t) {
    const float eu = fmaxf((z[t] - mu) * rstd * gv[t] + bv[t], 0.f);
    const float* wrow = w2eff + (size_t)(c0 + t) * kH;
#pragma unroll
    for (int h = 0; h < kH; ++h) acc[h] += eu * wrow[h];
  }
#pragma unroll
  for (int h = 0; h < kH; ++h) acc[h] = wsum(acc[h]);
  if (lane < kH)
    es[(((size_t)b * kS + i) * kS + jj + 1) * kH + lane] = acc[lane] + b2eff[lane];
}

// --------------------------------------------- attn softmax + context rows
// block per (b,i), 576 threads (9 waves): logits -> softmax -> attn out + ctx
__global__ __launch_bounds__(576) void attn_ctx(
    const float* __restrict__ sq, const float* __restrict__ sk,
    const float* __restrict__ es, const float* __restrict__ adj,
    const float* __restrict__ v, const float* __restrict__ b_attn,
    float* __restrict__ attn_out, float* __restrict__ ctx)
{
  __shared__ float prob[kH][kS];
  const int bi = blockIdx.x;
  const int b = bi / kS, i = bi % kS;
  const int tid = threadIdx.x;
  const float ba = b_attn[0];
  if (tid < kH * kS) {
    const int h = tid / kS, j = tid % kS;
    float lgv;
    if (j == 0) {
      lgv = -1e30f;                                   // column 0 always masked
    } else {
      const float a = (i == 0) ? 1.f : adj[((size_t)b * kN + (i - 1)) * kN + (j - 1)];
      lgv = sq[(b * kS + i) * kH + h] + sk[(b * kS + j) * kH + h]
          + es[(((size_t)b * kS + i) * kS + j) * kH + h] * a + ba;
    }
    prob[h][j] = lgv;
  }
  __syncthreads();
  const int w = tid >> 6, lane = tid & 63;
  if (w < kH) {
    const float x = prob[w][lane];
    const float xe = prob[w][64];
    float m = wmax(x);
    m = fmaxf(m, xe);
    const float e = expf(x - m);
    const float ee = expf(xe - m);
    const float s = wsum(e) + ee;
    const float inv = 1.f / s;
    prob[w][lane] = e * inv;
    if (lane == 0) prob[w][64] = ee * inv;
  }
  __syncthreads();
  if (tid < kH * kS) {
    const int h = tid / kS, j = tid % kS;
    attn_out[(((size_t)b * kH + h) * kS + i) * kS + j] = prob[h][j];
  }
  if (tid < kD) {
    const int h = tid >> 6, d = tid & 63;
    float a = 0.f;
#pragma unroll 4
    for (int j = 1; j < kS; ++j)
      a += prob[h][j] * v[((size_t)b * kS + j) * kD + h * kHD + d];
    ctx[((size_t)b * kS + i) * kD + tid] = a;
  }
}

// ---------------------------------------------------------------- launcher
extern "C" void kernel_launch(void* const* d_in, const int* in_sizes, int n_in,
                              void* d_out, int out_size, void* d_ws, size_t ws_size,
                              hipStream_t stream)
{
  const float* desc = (const float*)d_in[0];
  const float* nv   = (const float*)d_in[1];
  const float* w_gt = (const float*)d_in[2];
  const float* b_gt = (const float*)d_in[3];
  const float* topo = (const float*)d_in[4];
  const float* w_e1 = (const float*)d_in[5];
  const float* b_e1 = (const float*)d_in[6];
  const float* ln_g = (const float*)d_in[7];
  const float* ln_b = (const float*)d_in[8];
  const float* w_e2 = (const float*)d_in[9];
  const float* b_e2 = (const float*)d_in[10];
  const float* w_q  = (const float*)d_in[11];
  const float* b_q  = (const float*)d_in[12];
  const float* w_k  = (const float*)d_in[13];
  const float* b_k  = (const float*)d_in[14];
  const float* w_v  = (const float*)d_in[15];
  const float* b_v  = (const float*)d_in[16];
  const float* w_at = (const float*)d_in[17];
  const float* b_at = (const float*)d_in[18];
  const float* w_o  = (const float*)d_in[19];
  const float* b_o  = (const float*)d_in[20];

  // workspace layout (floats); total ~4.33M f32 = 17.33 MB
  float* ws  = (float*)d_ws;
  float* de  = ws;                    // B*N*D      = 524288
  float* q   = de  + 524288;          // B*S*D      = 532480
  float* k   = q   + 532480;
  float* v   = k   + 532480;
  float* Pp  = v   + 532480;          // B*N*D
  float* Qq  = Pp  + 524288;
  float* adj = Qq  + 524288;          // B*N*N      = 65536
  float* sq  = adj + 65536;           // B*S*H      = 8320
  float* sk  = sq  + 8320;
  float* es  = sk  + 8320;            // B*S*S*H    = 540800
  float* ctx = es  + 540800;          // B*S*D
  float* w2e = ctx + 532480;          // D*H        = 4096
  float* b2e = w2e + 4096;            // H
  float* ivd = b2e + 8;               // B*N
  float* ivv = ivd + 1024;            // B*N

  float* out  = (float*)d_out;                 // (B,S,D)
  float* attn = out + (size_t)kB * kS * kD;    // (B,H,S,S)

  prep_w2eff<<<513, 64, 0, stream>>>(w_e2, b_e2, w_at, w2e, b2e);

  // dispatch 2: de + q + k + v (independent; z-packed), grid 17x8x4 = 544 blocks
  {
    GJobs jobs;
    jobs.j[0] = { desc, w_gt, b_gt, de, kB * kN };
    jobs.j[1] = { nv,   w_q,  b_q,  q,  kB * kS };
    jobs.j[2] = { nv,   w_k,  b_k,  k,  kB * kS };
    jobs.j[3] = { nv,   w_v,  b_v,  v,  kB * kS };
    gemm_multi<<<dim3(17, 8, 4), 256, 0, stream>>>(jobs, kD, kD);
  }
  // dispatch 3: P = de@W1_top + b1, Q = de@W1_bot  (z-packed), 16x8x2 = 256 blocks
  {
    GJobs jobs;
    jobs.j[0] = { de, w_e1,           b_e1,    Pp, kB * kN };
    jobs.j[1] = { de, w_e1 + kD * kD, nullptr, Qq, kB * kN };
    jobs.j[2] = jobs.j[0]; jobs.j[3] = jobs.j[0];   // unused (gridDim.z = 2)
    gemm_multi<<<dim3(16, 8, 2), 256, 0, stream>>>(jobs, kD, kD);
  }

  norms_kernel<<<512, 256, 0, stream>>>(de, nv, ivd, ivv);
  adjacency_kernel<<<kB * kN, 256, 0, stream>>>(de, nv, ivd, ivv, topo, adj);
  qk_scores<<<65, 256, 0, stream>>>(q, k, w_at, sq, sk);
  edge_scores<<<16640, 256, 0, stream>>>(Pp, Qq, ln_g, ln_b, w2e, b2e, es);
  attn_ctx<<<kB * kS, 576, 0, stream>>>(sq, sk, es, adj, v, b_at, attn, ctx);

  // dispatch 8: output projection
  {
    GJobs jobs;
    jobs.j[0] = { ctx, w_o, b_o, out, kB * kS };
    jobs.j[1] = jobs.j[0]; jobs.j[2] = jobs.j[0]; jobs.j[3] = jobs.j[0];
    gemm_multi<<<dim3(17, 8, 1), 256, 0, stream>>>(jobs, kD, kD);
  }
}

// Round 5
// 449.742 us; speedup vs baseline: 1.0637x; 1.0637x over previous
//
#include <hip/hip_runtime.h>
#include <math.h>

// AdaptiveGraphAttention — MI355X f32, round 5 (= round-3 restructure; rounds 3-4
// never ran due to GPU acquisition timeouts; re-audited and resubmitted unchanged).
// R2 profile: edge_scores 139us, VALUBusy 16.6% -> latency-bound on 60 serial
// shfl chains/wave. Fix: 8-lanes-per-pair, 64 channels per lane, z in registers;
// reductions shrink 10x and gain 8-way ILP.

constexpr int kD  = 512;
constexpr int kH  = 8;
constexpr int kHD = 64;
constexpr int kB  = 16;
constexpr int kN  = 64;
constexpr int kS  = 65;

__device__ __forceinline__ float wsum(float x) {
#pragma unroll
  for (int m = 1; m < 64; m <<= 1) x += __shfl_xor(x, m, 64);
  return x;
}
__device__ __forceinline__ float wmax(float x) {
#pragma unroll
  for (int m = 1; m < 64; m <<= 1) x = fmaxf(x, __shfl_xor(x, m, 64));
  return x;
}
// reduce across the 8 channel-octants (lanes differing in bits 3..5)
__device__ __forceinline__ float osum(float x) {
  x += __shfl_xor(x, 8, 64);
  x += __shfl_xor(x, 16, 64);
  x += __shfl_xor(x, 32, 64);
  return x;
}

// ---------------------------------------------------------------- GEMM (f32)
#define BM 64
#define BN 64
#define BK 32

struct GJob { const float* A; const float* W; const float* bias; float* C; int M; };
struct GJobs { GJob j[4]; };

__global__ __launch_bounds__(256) void gemm_multi(GJobs jobs, int N, int K)
{
  const GJob jb = jobs.j[blockIdx.z];
  const float* __restrict__ A = jb.A;
  const float* __restrict__ W = jb.W;
  const float* __restrict__ bias = jb.bias;
  float* __restrict__ C = jb.C;
  const int M = jb.M;

  __shared__ float Ast[BK][BM + 1];
  __shared__ float Bs[BK][BN];
  const int bm = blockIdx.x * BM, bn = blockIdx.y * BN;
  const int tid = threadIdx.x;
  const int tx = tid & 15, ty = tid >> 4;
  float acc[4][4] = {};

  for (int k0 = 0; k0 < K; k0 += BK) {
    {
      const int kk = tid & 31, r0 = tid >> 5;
#pragma unroll
      for (int it = 0; it < 8; ++it) {
        const int r = r0 + it * 8;
        const int row = bm + r;
        Ast[kk][r] = (row < M) ? A[(size_t)row * K + k0 + kk] : 0.f;
      }
      const int n = tid & 63, kr0 = tid >> 6;
#pragma unroll
      for (int it = 0; it < 8; ++it) {
        const int kr = kr0 + it * 4;
        Bs[kr][n] = W[(size_t)(k0 + kr) * N + bn + n];
      }
    }
    __syncthreads();
#pragma unroll
    for (int kk = 0; kk < BK; ++kk) {
      const float a0 = Ast[kk][ty * 4 + 0];
      const float a1 = Ast[kk][ty * 4 + 1];
      const float a2 = Ast[kk][ty * 4 + 2];
      const float a3 = Ast[kk][ty * 4 + 3];
      const float4 bv = *reinterpret_cast<const float4*>(&Bs[kk][tx * 4]);
      acc[0][0] += a0 * bv.x; acc[0][1] += a0 * bv.y; acc[0][2] += a0 * bv.z; acc[0][3] += a0 * bv.w;
      acc[1][0] += a1 * bv.x; acc[1][1] += a1 * bv.y; acc[1][2] += a1 * bv.z; acc[1][3] += a1 * bv.w;
      acc[2][0] += a2 * bv.x; acc[2][1] += a2 * bv.y; acc[2][2] += a2 * bv.z; acc[2][3] += a2 * bv.w;
      acc[3][0] += a3 * bv.x; acc[3][1] += a3 * bv.y; acc[3][2] += a3 * bv.z; acc[3][3] += a3 * bv.w;
    }
    __syncthreads();
  }
#pragma unroll
  for (int i = 0; i < 4; ++i) {
    const int row = bm + ty * 4 + i;
    if (row < M) {
#pragma unroll
      for (int j = 0; j < 4; ++j) {
        const int col = bn + tx * 4 + j;
        const float b = bias ? bias[col] : 0.f;
        C[(size_t)row * N + col] = acc[i][j] + b;
      }
    }
  }
}

// -------------------------------------------------- fold w_edge2 with we_a
// thread per (c,h): w2eff[c,h] = sum_d w_edge2[c, h*64+d] * w_attn[128+d]
__global__ __launch_bounds__(256) void prep_w2eff(
    const float* __restrict__ w_edge2, const float* __restrict__ b_edge2,
    const float* __restrict__ w_attn,
    float* __restrict__ w2eff, float* __restrict__ b2eff)
{
  const int t = blockIdx.x * 256 + threadIdx.x;
  if (t >= (kD + 1) * kH) return;
  const int c = t >> 3, h = t & 7;
  const float* src = (c < kD) ? (w_edge2 + (size_t)c * kD + h * kHD)
                              : (b_edge2 + h * kHD);
  const float4* s4 = reinterpret_cast<const float4*>(src);
  const float4* wa4 = reinterpret_cast<const float4*>(w_attn + 2 * kHD);
  float acc = 0.f;
#pragma unroll
  for (int q = 0; q < kHD / 4; ++q) {
    const float4 a = s4[q], w = wa4[q];
    acc += a.x * w.x + a.y * w.y + a.z * w.z + a.w * w.w;
  }
  if (c < kD) w2eff[c * kH + h] = acc; else b2eff[h] = acc;
}

// ------------------------------------------------------- row inverse norms
__global__ __launch_bounds__(256) void norms_kernel(
    const float* __restrict__ de, const float* __restrict__ nv,
    float* __restrict__ invde, float* __restrict__ invvar)
{
  const int wid = blockIdx.x * 4 + (threadIdx.x >> 6);
  const int lane = threadIdx.x & 63;
  const float* row;
  if (wid < kB * kN) {
    row = de + (size_t)wid * kD;
  } else {
    const int t = wid - kB * kN;
    row = nv + ((size_t)(t / kN) * kS + 1 + (t % kN)) * kD;
  }
  const float4* r4 = reinterpret_cast<const float4*>(row) + lane * 2;
  const float4 x0 = r4[0], x1 = r4[1];
  float ss = x0.x * x0.x + x0.y * x0.y + x0.z * x0.z + x0.w * x0.w
           + x1.x * x1.x + x1.y * x1.y + x1.z * x1.z + x1.w * x1.w;
  ss = wsum(ss);
  if (lane == 0) {
    const float inv = 1.f / sqrtf(ss);
    if (wid < kB * kN) invde[wid] = inv; else invvar[wid - kB * kN] = inv;
  }
}

// ---------------------------------------------------------- adjacency rows
// block (512 thr, 8 waves) per (b,i); wave handles 8 j's, 8 lanes per j.
__global__ __launch_bounds__(512) void adjacency_kernel(
    const float* __restrict__ de, const float* __restrict__ nv,
    const float* __restrict__ invde, const float* __restrict__ invvar,
    const float* __restrict__ topo_p, float* __restrict__ adj)
{
  __shared__ float lg[kN];
  const int b = blockIdx.x >> 6, i = blockIdx.x & 63;
  const int w = threadIdx.x >> 6, lane = threadIdx.x & 63;
  const int p = lane & 7, oct = lane >> 3;
  const int j = w * 8 + p;
  const float topo = topo_p[0];
  const float4* di = reinterpret_cast<const float4*>(de + ((size_t)b * kN + i) * kD + oct * 64);
  const float4* dj = reinterpret_cast<const float4*>(de + ((size_t)b * kN + j) * kD + oct * 64);
  const float4* vi = reinterpret_cast<const float4*>(nv + ((size_t)b * kS + 1 + i) * kD + oct * 64);
  const float4* vj = reinterpret_cast<const float4*>(nv + ((size_t)b * kS + 1 + j) * kD + oct * 64);
  float g = 0.f, sv = 0.f;
#pragma unroll
  for (int t = 0; t < 16; ++t) {
    const float4 a = di[t], c = dj[t];
    g += a.x * c.x + a.y * c.y + a.z * c.z + a.w * c.w;
    const float4 x = vi[t], y = vj[t];
    sv += x.x * y.x + x.y * y.y + x.z * y.z + x.w * y.w;
  }
  g = osum(g);
  sv = osum(sv);
  if (oct == 0) {
    const float gs = g * invde[b * kN + i] * invde[b * kN + j] + topo;
    const bool hard = (gs > 0.f) && (j != i);   // sigmoid(x)>0.5 <=> x>0
    lg[j] = hard ? sv * invvar[b * kN + i] * invvar[b * kN + j] : 0.f;
  }
  __syncthreads();
  if (threadIdx.x < 64) {
    const float x = lg[lane];
    const float m = wmax(x);
    const float e = expf(x - m);
    const float s = wsum(e);
    adj[((size_t)b * kN + i) * kN + lane] = e / s;
  }
}

// --------------------------------------------------------- q/k attn scores
__global__ __launch_bounds__(256) void qk_scores(
    const float* __restrict__ q, const float* __restrict__ k,
    const float* __restrict__ w_attn,
    float* __restrict__ sq, float* __restrict__ sk)
{
  const int t = blockIdx.x * 256 + threadIdx.x;
  const int total = kB * kS * kH;
  const int which = (t >= total) ? 1 : 0;
  const int r = which ? t - total : t;
  const int h = r % kH, bs = r / kH;
  const float* src = which ? k : q;
  const float* wa = w_attn + which * kHD;
  const float4* row = reinterpret_cast<const float4*>(src + (size_t)bs * kD + h * kHD);
  const float4* w4 = reinterpret_cast<const float4*>(wa);
  float acc = 0.f;
#pragma unroll
  for (int c = 0; c < kHD / 4; ++c) {
    const float4 a = row[c], w = w4[c];
    acc += a.x * w.x + a.y * w.y + a.z * w.z + a.w * w.w;
  }
  (which ? sk : sq)[r] = acc;
}

// -------------------------------------------------------------- edge scores
// 8 lanes per pair (oct = lane>>3 owns 64 channels), z kept in registers.
// Per wave: 8 pairs. Reductions: 2x3 shfl (LN stats) + 8x3 shfl (head dots).
__global__ __launch_bounds__(256) void edge_scores(
    const float* __restrict__ Pp, const float* __restrict__ Qq,
    const float* __restrict__ gamma, const float* __restrict__ beta,
    const float* __restrict__ w2eff, const float* __restrict__ b2eff,
    float* __restrict__ es)
{
  const int wid = blockIdx.x * 4 + (threadIdx.x >> 6);
  const int lane = threadIdx.x & 63;
  const int p = lane & 7, oct = lane >> 3;
  const int pair = wid * 8 + p;                      // 0 .. B*S*N-1
  const int b = pair / (kS * kN);
  const int r = pair % (kS * kN);
  const int i = r / kN, jj = r % kN;                 // j = jj+1
  const int prow = b * kN + (i == 0 ? jj : i - 1);
  const int qrow = b * kN + jj;
  const int c0 = oct * 64;
  const float4* Pr = reinterpret_cast<const float4*>(Pp + (size_t)prow * kD + c0);
  const float4* Qr = reinterpret_cast<const float4*>(Qq + (size_t)qrow * kD + c0);

  float4 z4[16];
  float s1 = 0.f, s2 = 0.f;
#pragma unroll
  for (int t = 0; t < 16; ++t) {
    const float4 a = Pr[t], c = Qr[t];
    float4 z;
    z.x = a.x + c.x; z.y = a.y + c.y; z.z = a.z + c.z; z.w = a.w + c.w;
    z4[t] = z;
    s1 += (z.x + z.y) + (z.z + z.w);
    s2 += (z.x * z.x + z.y * z.y) + (z.z * z.z + z.w * z.w);
  }
  s1 = osum(s1);
  s2 = osum(s2);
  const float mu = s1 * (1.f / kD);
  const float var = s2 * (1.f / kD) - mu * mu;
  const float rstd = rsqrtf(var + 1e-5f);
  const float nb = -mu * rstd;

  float acc[8] = {};
#pragma unroll
  for (int t = 0; t < 16; ++t) {
    const float4 g4 = *reinterpret_cast<const float4*>(gamma + c0 + t * 4);
    const float4 b4 = *reinterpret_cast<const float4*>(beta + c0 + t * 4);
    const float zc[4] = { z4[t].x, z4[t].y, z4[t].z, z4[t].w };
    const float gc[4] = { g4.x, g4.y, g4.z, g4.w };
    const float bc[4] = { b4.x, b4.y, b4.z, b4.w };
#pragma unroll
    for (int u = 0; u < 4; ++u) {
      const float zn = fmaf(zc[u], rstd, nb);
      const float eu = fmaxf(fmaf(zn, gc[u], bc[u]), 0.f);
      const float4* w4 = reinterpret_cast<const float4*>(w2eff + (size_t)(c0 + t * 4 + u) * kH);
      const float4 wa = w4[0], wb = w4[1];
      acc[0] = fmaf(eu, wa.x, acc[0]); acc[1] = fmaf(eu, wa.y, acc[1]);
      acc[2] = fmaf(eu, wa.z, acc[2]); acc[3] = fmaf(eu, wa.w, acc[3]);
      acc[4] = fmaf(eu, wb.x, acc[4]); acc[5] = fmaf(eu, wb.y, acc[5]);
      acc[6] = fmaf(eu, wb.z, acc[6]); acc[7] = fmaf(eu, wb.w, acc[7]);
    }
  }
#pragma unroll
  for (int h = 0; h < 8; ++h) acc[h] = osum(acc[h]);
  if (oct == 0) {
    const float4 ba0 = *reinterpret_cast<const float4*>(b2eff);
    const float4 ba1 = *reinterpret_cast<const float4*>(b2eff + 4);
    float* dst = es + (((size_t)b * kS + i) * kS + jj + 1) * kH;
    float4 o0, o1;
    o0.x = acc[0] + ba0.x; o0.y = acc[1] + ba0.y; o0.z = acc[2] + ba0.z; o0.w = acc[3] + ba0.w;
    o1.x = acc[4] + ba1.x; o1.y = acc[5] + ba1.y; o1.z = acc[6] + ba1.z; o1.w = acc[7] + ba1.w;
    reinterpret_cast<float4*>(dst)[0] = o0;
    reinterpret_cast<float4*>(dst)[1] = o1;
  }
}

// --------------------------------------------- attn softmax + context rows
__global__ __launch_bounds__(576) void attn_ctx(
    const float* __restrict__ sq, const float* __restrict__ sk,
    const float* __restrict__ es, const float* __restrict__ adj,
    const float* __restrict__ v, const float* __restrict__ b_attn,
    float* __restrict__ attn_out, float* __restrict__ ctx)
{
  __shared__ float prob[kH][kS];
  const int bi = blockIdx.x;
  const int b = bi / kS, i = bi % kS;
  const int tid = threadIdx.x;
  const float ba = b_attn[0];
  if (tid < kH * kS) {
    const int h = tid / kS, j = tid % kS;
    float lgv;
    if (j == 0) {
      lgv = -1e30f;
    } else {
      const float a = (i == 0) ? 1.f : adj[((size_t)b * kN + (i - 1)) * kN + (j - 1)];
      lgv = sq[(b * kS + i) * kH + h] + sk[(b * kS + j) * kH + h]
          + es[(((size_t)b * kS + i) * kS + j) * kH + h] * a + ba;
    }
    prob[h][j] = lgv;
  }
  __syncthreads();
  const int w = tid >> 6, lane = tid & 63;
  if (w < kH) {
    const float x = prob[w][lane];
    const float xe = prob[w][64];
    float m = wmax(x);
    m = fmaxf(m, xe);
    const float e = expf(x - m);
    const float ee = expf(xe - m);
    const float s = wsum(e) + ee;
    const float inv = 1.f / s;
    prob[w][lane] = e * inv;
    if (lane == 0) prob[w][64] = ee * inv;
  }
  __syncthreads();
  if (tid < kH * kS) {
    const int h = tid / kS, j = tid % kS;
    attn_out[(((size_t)b * kH + h) * kS + i) * kS + j] = prob[h][j];
  }
  if (tid < kD) {
    const int h = tid >> 6, d = tid & 63;
    const float* vb = v + (size_t)b * kS * kD + h * kHD + d;
    float a0 = 0.f, a1 = 0.f, a2 = 0.f, a3 = 0.f;
#pragma unroll 4
    for (int j = 1; j < kS; j += 4) {
      a0 = fmaf(prob[h][j + 0], vb[(size_t)(j + 0) * kD], a0);
      a1 = fmaf(prob[h][j + 1], vb[(size_t)(j + 1) * kD], a1);
      a2 = fmaf(prob[h][j + 2], vb[(size_t)(j + 2) * kD], a2);
      a3 = fmaf(prob[h][j + 3], vb[(size_t)(j + 3) * kD], a3);
    }
    ctx[((size_t)b * kS + i) * kD + tid] = (a0 + a1) + (a2 + a3);
  }
}

// ---------------------------------------------------------------- launcher
extern "C" void kernel_launch(void* const* d_in, const int* in_sizes, int n_in,
                              void* d_out, int out_size, void* d_ws, size_t ws_size,
                              hipStream_t stream)
{
  const float* desc = (const float*)d_in[0];
  const float* nv   = (const float*)d_in[1];
  const float* w_gt = (const float*)d_in[2];
  const float* b_gt = (const float*)d_in[3];
  const float* topo = (const float*)d_in[4];
  const float* w_e1 = (const float*)d_in[5];
  const float* b_e1 = (const float*)d_in[6];
  const float* ln_g = (const float*)d_in[7];
  const float* ln_b = (const float*)d_in[8];
  const float* w_e2 = (const float*)d_in[9];
  const float* b_e2 = (const float*)d_in[10];
  const float* w_q  = (const float*)d_in[11];
  const float* b_q  = (const float*)d_in[12];
  const float* w_k  = (const float*)d_in[13];
  const float* b_k  = (const float*)d_in[14];
  const float* w_v  = (const float*)d_in[15];
  const float* b_v  = (const float*)d_in[16];
  const float* w_at = (const float*)d_in[17];
  const float* b_at = (const float*)d_in[18];
  const float* w_o  = (const float*)d_in[19];
  const float* b_o  = (const float*)d_in[20];

  float* ws  = (float*)d_ws;
  float* de  = ws;                    // B*N*D
  float* q   = de  + 524288;          // B*S*D
  float* k   = q   + 532480;
  float* v   = k   + 532480;
  float* Pp  = v   + 532480;          // B*N*D
  float* Qq  = Pp  + 524288;
  float* adj = Qq  + 524288;          // B*N*N
  float* sq  = adj + 65536;           // B*S*H
  float* sk  = sq  + 8320;
  float* es  = sk  + 8320;            // B*S*S*H
  float* ctx = es  + 540800;          // B*S*D
  float* w2e = ctx + 532480;          // D*H
  float* b2e = w2e + 4096;            // H
  float* ivd = b2e + 8;               // B*N
  float* ivv = ivd + 1024;            // B*N

  float* out  = (float*)d_out;                 // (B,S,D)
  float* attn = out + (size_t)kB * kS * kD;    // (B,H,S,S)

  prep_w2eff<<<17, 256, 0, stream>>>(w_e2, b_e2, w_at, w2e, b2e);

  {
    GJobs jobs;
    jobs.j[0] = { desc, w_gt, b_gt, de, kB * kN };
    jobs.j[1] = { nv,   w_q,  b_q,  q,  kB * kS };
    jobs.j[2] = { nv,   w_k,  b_k,  k,  kB * kS };
    jobs.j[3] = { nv,   w_v,  b_v,  v,  kB * kS };
    gemm_multi<<<dim3(17, 8, 4), 256, 0, stream>>>(jobs, kD, kD);
  }
  {
    GJobs jobs;
    jobs.j[0] = { de, w_e1,           b_e1,    Pp, kB * kN };
    jobs.j[1] = { de, w_e1 + kD * kD, nullptr, Qq, kB * kN };
    jobs.j[2] = jobs.j[0]; jobs.j[3] = jobs.j[0];
    gemm_multi<<<dim3(16, 8, 2), 256, 0, stream>>>(jobs, kD, kD);
  }

  norms_kernel<<<512, 256, 0, stream>>>(de, nv, ivd, ivv);
  adjacency_kernel<<<kB * kN, 512, 0, stream>>>(de, nv, ivd, ivv, topo, adj);
  qk_scores<<<65, 256, 0, stream>>>(q, k, w_at, sq, sk);
  edge_scores<<<2080, 256, 0, stream>>>(Pp, Qq, ln_g, ln_b, w2e, b2e, es);
  attn_ctx<<<kB * kS, 576, 0, stream>>>(sq, sk, es, adj, v, b_at, attn, ctx);

  {
    GJobs jobs;
    jobs.j[0] = { ctx, w_o, b_o, out, kB * kS };
    jobs.j[1] = jobs.j[0]; jobs.j[2] = jobs.j[0]; jobs.j[3] = jobs.j[0];
    gemm_multi<<<dim3(17, 8, 1), 256, 0, stream>>>(jobs, kD, kD);
  }
}

// Round 6
// 396.386 us; speedup vs baseline: 1.2069x; 1.1346x over previous
//
#include <hip/hip_runtime.h>
#include <math.h>

// AdaptiveGraphAttention — MI355X f32, round 6.
// R5 profile: gemm_multi(z4) 89us @ VALUBusy 20%, Occ 21.7% (grid-capped),
// 474 GB/s latency-bound staging. Fix: split-K (atomicAdd into zeroed C),
// float4 staging with register prefetch, kernel fusion (norms into PQ-gemm
// dispatch; qk+prep into adjacency dispatch). 9 kernels -> 6 (+2 memsets).

constexpr int kD  = 512;
constexpr int kH  = 8;
constexpr int kHD = 64;
constexpr int kB  = 16;
constexpr int kN  = 64;
constexpr int kS  = 65;

__device__ __forceinline__ float wsum(float x) {
#pragma unroll
  for (int m = 1; m < 64; m <<= 1) x += __shfl_xor(x, m, 64);
  return x;
}
__device__ __forceinline__ float wmax(float x) {
#pragma unroll
  for (int m = 1; m < 64; m <<= 1) x = fmaxf(x, __shfl_xor(x, m, 64));
  return x;
}
__device__ __forceinline__ float osum(float x) {
  x += __shfl_xor(x, 8, 64);
  x += __shfl_xor(x, 16, 64);
  x += __shfl_xor(x, 32, 64);
  return x;
}

// --------------------------------------------------------- GEMM (f32 splitK)
// C[M,512] += A[M,512-chunk] @ W[chunk,512] (+bias on chunk 0), via atomicAdd
// into pre-zeroed C. 256 thr, BM=BN=64, BK=32, float4 staging + reg prefetch.
#define BM 64
#define BN 64
#define BK 32

struct GJob { const float* A; const float* W; const float* bias; float* C; int M; };
struct GJobs { GJob j[4]; };

__global__ __launch_bounds__(256) void gemm_splitk(
    GJobs jobs, int ksplit, int kib, int zNorms,
    const float* __restrict__ de, const float* __restrict__ nv,
    float* __restrict__ invde, float* __restrict__ invvar)
{
  if ((int)blockIdx.z == zNorms) {
    // ---- row inverse norms: 128 blocks x 16 rows (4 waves x 4 rows) ----
    const int flat = blockIdx.x + gridDim.x * blockIdx.y;
    if (flat < 128) {
      const int lane = threadIdx.x & 63;
      const int w = threadIdx.x >> 6;
#pragma unroll
      for (int r = 0; r < 4; ++r) {
        const int wid = flat * 16 + w * 4 + r;
        const float* row;
        if (wid < kB * kN) {
          row = de + (size_t)wid * kD;
        } else {
          const int t = wid - kB * kN;
          row = nv + ((size_t)(t / kN) * kS + 1 + (t % kN)) * kD;
        }
        const float4* r4 = reinterpret_cast<const float4*>(row) + lane * 2;
        const float4 x0 = r4[0], x1 = r4[1];
        float ss = x0.x * x0.x + x0.y * x0.y + x0.z * x0.z + x0.w * x0.w
                 + x1.x * x1.x + x1.y * x1.y + x1.z * x1.z + x1.w * x1.w;
        ss = wsum(ss);
        if (lane == 0) {
          const float inv = 1.f / sqrtf(ss);
          if (wid < kB * kN) invde[wid] = inv; else invvar[wid - kB * kN] = inv;
        }
      }
    }
    return;
  }

  const int job = blockIdx.z / ksplit, chunk = blockIdx.z % ksplit;
  const GJob jb = jobs.j[job];
  const float* __restrict__ A = jb.A;
  const float* __restrict__ W = jb.W;
  const float* __restrict__ bias = jb.bias;
  float* __restrict__ C = jb.C;
  const int M = jb.M;
  const int bm = blockIdx.x * BM, bn = blockIdx.y * BN;
  if (bm >= M) return;

  __shared__ float Ast[BK][BM + 1];
  __shared__ float Bs[BK][BN];
  const int tid = threadIdx.x;
  const int ar = tid >> 2, ak = (tid & 3) * 8;        // A: row, k-offset (8 f32)
  const int bkr = tid >> 3, bn0 = (tid & 7) * 8;      // B: k-row, n-offset (8 f32)
  const int tx = tid & 15, ty = tid >> 4;
  const int k0 = chunk * kib * BK;
  const bool aval = (bm + ar) < M;
  const float* Ap = A + (size_t)(bm + ar) * kD + k0 + ak;
  const float* Wp = W + (size_t)(k0 + bkr) * kD + bn + bn0;
  const float4 f4z = { 0.f, 0.f, 0.f, 0.f };

  float4 a0, a1, b0, b1;
  a0 = aval ? *reinterpret_cast<const float4*>(Ap)     : f4z;
  a1 = aval ? *reinterpret_cast<const float4*>(Ap + 4) : f4z;
  b0 = *reinterpret_cast<const float4*>(Wp);
  b1 = *reinterpret_cast<const float4*>(Wp + 4);

  float acc[4][4] = {};
  for (int kt = 0; kt < kib; ++kt) {
    Ast[ak + 0][ar] = a0.x; Ast[ak + 1][ar] = a0.y;
    Ast[ak + 2][ar] = a0.z; Ast[ak + 3][ar] = a0.w;
    Ast[ak + 4][ar] = a1.x; Ast[ak + 5][ar] = a1.y;
    Ast[ak + 6][ar] = a1.z; Ast[ak + 7][ar] = a1.w;
    *reinterpret_cast<float4*>(&Bs[bkr][bn0])     = b0;
    *reinterpret_cast<float4*>(&Bs[bkr][bn0 + 4]) = b1;
    __syncthreads();
    if (kt + 1 < kib) {                       // prefetch next tile into regs
      const float* Ap2 = Ap + (kt + 1) * BK;
      const float* Wp2 = Wp + (size_t)(kt + 1) * BK * kD;
      a0 = aval ? *reinterpret_cast<const float4*>(Ap2)     : f4z;
      a1 = aval ? *reinterpret_cast<const float4*>(Ap2 + 4) : f4z;
      b0 = *reinterpret_cast<const float4*>(Wp2);
      b1 = *reinterpret_cast<const float4*>(Wp2 + 4);
    }
#pragma unroll
    for (int kk = 0; kk < BK; ++kk) {
      const float x0 = Ast[kk][ty * 4 + 0];
      const float x1 = Ast[kk][ty * 4 + 1];
      const float x2 = Ast[kk][ty * 4 + 2];
      const float x3 = Ast[kk][ty * 4 + 3];
      const float4 bv = *reinterpret_cast<const float4*>(&Bs[kk][tx * 4]);
      acc[0][0] = fmaf(x0, bv.x, acc[0][0]); acc[0][1] = fmaf(x0, bv.y, acc[0][1]);
      acc[0][2] = fmaf(x0, bv.z, acc[0][2]); acc[0][3] = fmaf(x0, bv.w, acc[0][3]);
      acc[1][0] = fmaf(x1, bv.x, acc[1][0]); acc[1][1] = fmaf(x1, bv.y, acc[1][1]);
      acc[1][2] = fmaf(x1, bv.z, acc[1][2]); acc[1][3] = fmaf(x1, bv.w, acc[1][3]);
      acc[2][0] = fmaf(x2, bv.x, acc[2][0]); acc[2][1] = fmaf(x2, bv.y, acc[2][1]);
      acc[2][2] = fmaf(x2, bv.z, acc[2][2]); acc[2][3] = fmaf(x2, bv.w, acc[2][3]);
      acc[3][0] = fmaf(x3, bv.x, acc[3][0]); acc[3][1] = fmaf(x3, bv.y, acc[3][1]);
      acc[3][2] = fmaf(x3, bv.z, acc[3][2]); acc[3][3] = fmaf(x3, bv.w, acc[3][3]);
    }
    __syncthreads();
  }
#pragma unroll
  for (int i = 0; i < 4; ++i) {
    const int row = bm + ty * 4 + i;
    if (row < M) {
#pragma unroll
      for (int j = 0; j < 4; ++j) {
        const int col = bn + tx * 4 + j;
        float val = acc[i][j];
        if (chunk == 0 && bias) val += bias[col];
        atomicAdd(&C[(size_t)row * kD + col], val);
      }
    }
  }
}

// ------------------------------------------- fused: adjacency + qk + w2eff
// 512 threads. blocks [0,1024): adjacency; [1024,1057): qk; [1057,1066): prep.
__global__ __launch_bounds__(512) void graph_prep(
    const float* __restrict__ de, const float* __restrict__ nv,
    const float* __restrict__ invde, const float* __restrict__ invvar,
    const float* __restrict__ topo_p, float* __restrict__ adj,
    const float* __restrict__ q, const float* __restrict__ k,
    const float* __restrict__ w_attn,
    float* __restrict__ sq, float* __restrict__ sk,
    const float* __restrict__ w_edge2, const float* __restrict__ b_edge2,
    float* __restrict__ w2eff, float* __restrict__ b2eff)
{
  const int blk = blockIdx.x;
  if (blk < kB * kN) {
    // ------------------------------ adjacency: block per (b,i), 8 lanes/j
    __shared__ float lg[kN];
    const int b = blk >> 6, i = blk & 63;
    const int w = threadIdx.x >> 6, lane = threadIdx.x & 63;
    const int p = lane & 7, oct = lane >> 3;
    const int j = w * 8 + p;
    const float topo = topo_p[0];
    const float4* di = reinterpret_cast<const float4*>(de + ((size_t)b * kN + i) * kD + oct * 64);
    const float4* dj = reinterpret_cast<const float4*>(de + ((size_t)b * kN + j) * kD + oct * 64);
    const float4* vi = reinterpret_cast<const float4*>(nv + ((size_t)b * kS + 1 + i) * kD + oct * 64);
    const float4* vj = reinterpret_cast<const float4*>(nv + ((size_t)b * kS + 1 + j) * kD + oct * 64);
    float g = 0.f, sv = 0.f;
#pragma unroll
    for (int t = 0; t < 16; ++t) {
      const float4 a = di[t], c = dj[t];
      g += a.x * c.x + a.y * c.y + a.z * c.z + a.w * c.w;
      const float4 x = vi[t], y = vj[t];
      sv += x.x * y.x + x.y * y.y + x.z * y.z + x.w * y.w;
    }
    g = osum(g);
    sv = osum(sv);
    if (oct == 0) {
      const float gs = g * invde[b * kN + i] * invde[b * kN + j] + topo;
      const bool hard = (gs > 0.f) && (j != i);   // sigmoid(x)>0.5 <=> x>0
      lg[j] = hard ? sv * invvar[b * kN + i] * invvar[b * kN + j] : 0.f;
    }
    __syncthreads();
    if (threadIdx.x < 64) {
      const float x = lg[lane];
      const float m = wmax(x);
      const float e = expf(x - m);
      const float s = wsum(e);
      adj[((size_t)b * kN + i) * kN + lane] = e / s;
    }
    return;
  }
  if (blk < kB * kN + 33) {
    // ------------------------------------------------------- q/k scores
    const int t = (blk - kB * kN) * 512 + threadIdx.x;
    const int total = kB * kS * kH;
    if (t >= 2 * total) return;
    const int which = (t >= total) ? 1 : 0;
    const int r = which ? t - total : t;
    const int h = r % kH, bs = r / kH;
    const float* src = which ? k : q;
    const float* wa = w_attn + which * kHD;
    const float4* row = reinterpret_cast<const float4*>(src + (size_t)bs * kD + h * kHD);
    const float4* w4 = reinterpret_cast<const float4*>(wa);
    float acc = 0.f;
#pragma unroll
    for (int c = 0; c < kHD / 4; ++c) {
      const float4 a = row[c], w = w4[c];
      acc += a.x * w.x + a.y * w.y + a.z * w.z + a.w * w.w;
    }
    (which ? sk : sq)[r] = acc;
    return;
  }
  {
    // ------------------------------------------- fold w_edge2 with we_a
    const int t = (blk - kB * kN - 33) * 512 + threadIdx.x;
    if (t >= (kD + 1) * kH) return;
    const int c = t >> 3, h = t & 7;
    const float* src = (c < kD) ? (w_edge2 + (size_t)c * kD + h * kHD)
                                : (b_edge2 + h * kHD);
    const float4* s4 = reinterpret_cast<const float4*>(src);
    const float4* wa4 = reinterpret_cast<const float4*>(w_attn + 2 * kHD);
    float acc = 0.f;
#pragma unroll
    for (int u = 0; u < kHD / 4; ++u) {
      const float4 a = s4[u], w = wa4[u];
      acc += a.x * w.x + a.y * w.y + a.z * w.z + a.w * w.w;
    }
    if (c < kD) w2eff[c * kH + h] = acc; else b2eff[h] = acc;
  }
}

// -------------------------------------------------------------- edge scores
// 8 lanes per pair (oct owns 64 channels), z in registers.
__global__ __launch_bounds__(256) void edge_scores(
    const float* __restrict__ Pp, const float* __restrict__ Qq,
    const float* __restrict__ gamma, const float* __restrict__ beta,
    const float* __restrict__ w2eff, const float* __restrict__ b2eff,
    float* __restrict__ es)
{
  const int wid = blockIdx.x * 4 + (threadIdx.x >> 6);
  const int lane = threadIdx.x & 63;
  const int p = lane & 7, oct = lane >> 3;
  const int pair = wid * 8 + p;                      // 0 .. B*S*N-1
  const int b = pair / (kS * kN);
  const int r = pair % (kS * kN);
  const int i = r / kN, jj = r % kN;                 // j = jj+1
  const int prow = b * kN + (i == 0 ? jj : i - 1);
  const int qrow = b * kN + jj;
  const int c0 = oct * 64;
  const float4* Pr = reinterpret_cast<const float4*>(Pp + (size_t)prow * kD + c0);
  const float4* Qr = reinterpret_cast<const float4*>(Qq + (size_t)qrow * kD + c0);

  float4 z4[16];
  float s1 = 0.f, s2 = 0.f;
#pragma unroll
  for (int t = 0; t < 16; ++t) {
    const float4 a = Pr[t], c = Qr[t];
    float4 z;
    z.x = a.x + c.x; z.y = a.y + c.y; z.z = a.z + c.z; z.w = a.w + c.w;
    z4[t] = z;
    s1 += (z.x + z.y) + (z.z + z.w);
    s2 += (z.x * z.x + z.y * z.y) + (z.z * z.z + z.w * z.w);
  }
  s1 = osum(s1);
  s2 = osum(s2);
  const float mu = s1 * (1.f / kD);
  const float var = s2 * (1.f / kD) - mu * mu;
  const float rstd = rsqrtf(var + 1e-5f);
  const float nb = -mu * rstd;

  float acc[8] = {};
#pragma unroll
  for (int t = 0; t < 16; ++t) {
    const float4 g4 = *reinterpret_cast<const float4*>(gamma + c0 + t * 4);
    const float4 b4 = *reinterpret_cast<const float4*>(beta + c0 + t * 4);
    const float zc[4] = { z4[t].x, z4[t].y, z4[t].z, z4[t].w };
    const float gc[4] = { g4.x, g4.y, g4.z, g4.w };
    const float bc[4] = { b4.x, b4.y, b4.z, b4.w };
#pragma unroll
    for (int u = 0; u < 4; ++u) {
      const float zn = fmaf(zc[u], rstd, nb);
      const float eu = fmaxf(fmaf(zn, gc[u], bc[u]), 0.f);
      const float4* w4 = reinterpret_cast<const float4*>(w2eff + (size_t)(c0 + t * 4 + u) * kH);
      const float4 wa = w4[0], wb = w4[1];
      acc[0] = fmaf(eu, wa.x, acc[0]); acc[1] = fmaf(eu, wa.y, acc[1]);
      acc[2] = fmaf(eu, wa.z, acc[2]); acc[3] = fmaf(eu, wa.w, acc[3]);
      acc[4] = fmaf(eu, wb.x, acc[4]); acc[5] = fmaf(eu, wb.y, acc[5]);
      acc[6] = fmaf(eu, wb.z, acc[6]); acc[7] = fmaf(eu, wb.w, acc[7]);
    }
  }
#pragma unroll
  for (int h = 0; h < 8; ++h) acc[h] = osum(acc[h]);
  if (oct == 0) {
    const float4 ba0 = *reinterpret_cast<const float4*>(b2eff);
    const float4 ba1 = *reinterpret_cast<const float4*>(b2eff + 4);
    float* dst = es + (((size_t)b * kS + i) * kS + jj + 1) * kH;
    float4 o0, o1;
    o0.x = acc[0] + ba0.x; o0.y = acc[1] + ba0.y; o0.z = acc[2] + ba0.z; o0.w = acc[3] + ba0.w;
    o1.x = acc[4] + ba1.x; o1.y = acc[5] + ba1.y; o1.z = acc[6] + ba1.z; o1.w = acc[7] + ba1.w;
    reinterpret_cast<float4*>(dst)[0] = o0;
    reinterpret_cast<float4*>(dst)[1] = o1;
  }
}

// --------------------------------------------- attn softmax + context rows
__global__ __launch_bounds__(576) void attn_ctx(
    const float* __restrict__ sq, const float* __restrict__ sk,
    const float* __restrict__ es, const float* __restrict__ adj,
    const float* __restrict__ v, const float* __restrict__ b_attn,
    float* __restrict__ attn_out, float* __restrict__ ctx)
{
  __shared__ float prob[kH][kS];
  const int bi = blockIdx.x;
  const int b = bi / kS, i = bi % kS;
  const int tid = threadIdx.x;
  const float ba = b_attn[0];
  if (tid < kH * kS) {
    const int h = tid / kS, j = tid % kS;
    float lgv;
    if (j == 0) {
      lgv = -1e30f;
    } else {
      const float a = (i == 0) ? 1.f : adj[((size_t)b * kN + (i - 1)) * kN + (j - 1)];
      lgv = sq[(b * kS + i) * kH + h] + sk[(b * kS + j) * kH + h]
          + es[(((size_t)b * kS + i) * kS + j) * kH + h] * a + ba;
    }
    prob[h][j] = lgv;
  }
  __syncthreads();
  const int w = tid >> 6, lane = tid & 63;
  if (w < kH) {
    const float x = prob[w][lane];
    const float xe = prob[w][64];
    float m = wmax(x);
    m = fmaxf(m, xe);
    const float e = expf(x - m);
    const float ee = expf(xe - m);
    const float s = wsum(e) + ee;
    const float inv = 1.f / s;
    prob[w][lane] = e * inv;
    if (lane == 0) prob[w][64] = ee * inv;
  }
  __syncthreads();
  if (tid < kH * kS) {
    const int h = tid / kS, j = tid % kS;
    attn_out[(((size_t)b * kH + h) * kS + i) * kS + j] = prob[h][j];
  }
  if (tid < kD) {
    const int h = tid >> 6, d = tid & 63;
    const float* vb = v + (size_t)b * kS * kD + h * kHD + d;
    float a0 = 0.f, a1 = 0.f, a2 = 0.f, a3 = 0.f;
#pragma unroll 4
    for (int j = 1; j < kS; j += 4) {
      a0 = fmaf(prob[h][j + 0], vb[(size_t)(j + 0) * kD], a0);
      a1 = fmaf(prob[h][j + 1], vb[(size_t)(j + 1) * kD], a1);
      a2 = fmaf(prob[h][j + 2], vb[(size_t)(j + 2) * kD], a2);
      a3 = fmaf(prob[h][j + 3], vb[(size_t)(j + 3) * kD], a3);
    }
    ctx[((size_t)b * kS + i) * kD + tid] = (a0 + a1) + (a2 + a3);
  }
}

// ---------------------------------------------------------------- launcher
extern "C" void kernel_launch(void* const* d_in, const int* in_sizes, int n_in,
                              void* d_out, int out_size, void* d_ws, size_t ws_size,
                              hipStream_t stream)
{
  const float* desc = (const float*)d_in[0];
  const float* nv   = (const float*)d_in[1];
  const float* w_gt = (const float*)d_in[2];
  const float* b_gt = (const float*)d_in[3];
  const float* topo = (const float*)d_in[4];
  const float* w_e1 = (const float*)d_in[5];
  const float* b_e1 = (const float*)d_in[6];
  const float* ln_g = (const float*)d_in[7];
  const float* ln_b = (const float*)d_in[8];
  const float* w_e2 = (const float*)d_in[9];
  const float* b_e2 = (const float*)d_in[10];
  const float* w_q  = (const float*)d_in[11];
  const float* b_q  = (const float*)d_in[12];
  const float* w_k  = (const float*)d_in[13];
  const float* b_k  = (const float*)d_in[14];
  const float* w_v  = (const float*)d_in[15];
  const float* b_v  = (const float*)d_in[16];
  const float* w_at = (const float*)d_in[17];
  const float* b_at = (const float*)d_in[18];
  const float* w_o  = (const float*)d_in[19];
  const float* b_o  = (const float*)d_in[20];

  float* ws  = (float*)d_ws;
  float* de  = ws;                    // B*N*D   (zeroed: gemm atomic target)
  float* q   = de  + 524288;          // B*S*D   (zeroed)
  float* k   = q   + 532480;          //         (zeroed)
  float* v   = k   + 532480;          //         (zeroed)
  float* Pp  = v   + 532480;          // B*N*D   (zeroed)
  float* Qq  = Pp  + 524288;          //         (zeroed)
  float* adj = Qq  + 524288;          // B*N*N
  float* sq  = adj + 65536;           // B*S*H
  float* sk  = sq  + 8320;
  float* es  = sk  + 8320;            // B*S*S*H
  float* ctx = es  + 540800;          // B*S*D
  float* w2e = ctx + 532480;          // D*H
  float* b2e = w2e + 4096;            // H
  float* ivd = b2e + 8;               // B*N
  float* ivv = ivd + 1024;            // B*N

  float* out  = (float*)d_out;                 // (B,S,D)  (zeroed: atomic target)
  float* attn = out + (size_t)kB * kS * kD;    // (B,H,S,S)

  // zero the atomicAdd targets: de..Qq contiguous (3,170,304 f32), and out
  hipMemsetAsync(de,  0, 3170304u * sizeof(float), stream);
  hipMemsetAsync(out, 0, (size_t)kB * kS * kD * sizeof(float), stream);

  // D1: de,q,k,v — splitK=2, grid (17,8,8) = 1088 blocks
  {
    GJobs jobs;
    jobs.j[0] = { desc, w_gt, b_gt, de, kB * kN };
    jobs.j[1] = { nv,   w_q,  b_q,  q,  kB * kS };
    jobs.j[2] = { nv,   w_k,  b_k,  k,  kB * kS };
    jobs.j[3] = { nv,   w_v,  b_v,  v,  kB * kS };
    gemm_splitk<<<dim3(17, 8, 8), 256, 0, stream>>>(jobs, 2, 8, -1,
                                                    nullptr, nullptr, nullptr, nullptr);
  }
  // D2: P,Q — splitK=2, + norms as z=4 slice; grid (16,8,5) = 640 blocks
  {
    GJobs jobs;
    jobs.j[0] = { de, w_e1,           b_e1,    Pp, kB * kN };
    jobs.j[1] = { de, w_e1 + kD * kD, nullptr, Qq, kB * kN };
    jobs.j[2] = jobs.j[0]; jobs.j[3] = jobs.j[0];
    gemm_splitk<<<dim3(16, 8, 5), 256, 0, stream>>>(jobs, 2, 8, 4,
                                                    de, nv, ivd, ivv);
  }
  // D3: adjacency (1024) + qk (33) + w2eff fold (9)
  graph_prep<<<1066, 512, 0, stream>>>(de, nv, ivd, ivv, topo, adj,
                                       q, k, w_at, sq, sk,
                                       w_e2, b_e2, w2e, b2e);
  // D4: edge scores
  edge_scores<<<2080, 256, 0, stream>>>(Pp, Qq, ln_g, ln_b, w2e, b2e, es);
  // D5: attention softmax + context
  attn_ctx<<<kB * kS, 576, 0, stream>>>(sq, sk, es, adj, v, b_at, attn, ctx);
  // D6: output projection — splitK=4, grid (17,8,4) = 544 blocks
  {
    GJobs jobs;
    jobs.j[0] = { ctx, w_o, b_o, out, kB * kS };
    jobs.j[1] = jobs.j[0]; jobs.j[2] = jobs.j[0]; jobs.j[3] = jobs.j[0];
    gemm_splitk<<<dim3(17, 8, 4), 256, 0, stream>>>(jobs, 4, 4, -1,
                                                    nullptr, nullptr, nullptr, nullptr);
  }
}

// Round 10
// 315.506 us; speedup vs baseline: 1.5163x; 1.2563x over previous
//
#include <hip/hip_runtime.h>
#include <math.h>

// AdaptiveGraphAttention — MI355X, round 10 (= round-9 MFMA kernel, resubmitted
// verbatim after the 6th GPU acquisition timeout; still unbenchmarked).
// R6 measured: f32 GEMM latency-bound (VALUBusy 21%, Occ 32%), splitK atomics
// blew WRITE_SIZE to 66MB, 549K LDS bank conflicts. Fix: bf16 hi/lo split
// 3-pass MFMA (16x16x32) for q,k,v,P,Q,out (smooth paths); de stays f32 (hard
// threshold sign safety). Weights pre-transposed+converted once per call.
// bf16 fragments use the guide-verified short8 ext-vector form.

constexpr int kD  = 512;
constexpr int kH  = 8;
constexpr int kHD = 64;
constexpr int kB  = 16;
constexpr int kN  = 64;
constexpr int kS  = 65;

typedef short bf16x8 __attribute__((ext_vector_type(8)));   // 8 bf16 bit-patterns
typedef float f32x4  __attribute__((ext_vector_type(4)));

__device__ __forceinline__ float wsum(float x) {
#pragma unroll
  for (int m = 1; m < 64; m <<= 1) x += __shfl_xor(x, m, 64);
  return x;
}
__device__ __forceinline__ float wmax(float x) {
#pragma unroll
  for (int m = 1; m < 64; m <<= 1) x = fmaxf(x, __shfl_xor(x, m, 64));
  return x;
}
__device__ __forceinline__ float osum(float x) {
  x += __shfl_xor(x, 8, 64);
  x += __shfl_xor(x, 16, 64);
  x += __shfl_xor(x, 32, 64);
  return x;
}

__device__ __forceinline__ unsigned short f2bf(float x) {   // RNE f32->bf16
  unsigned int u = __builtin_bit_cast(unsigned int, x);
  u += 0x7FFFu + ((u >> 16) & 1u);
  return (unsigned short)(u >> 16);
}
__device__ __forceinline__ float bf2f(unsigned short h) {
  return __builtin_bit_cast(float, ((unsigned int)h) << 16);
}
__device__ __forceinline__ unsigned int pk2(unsigned short a, unsigned short b) {
  return (unsigned int)a | ((unsigned int)b << 16);
}

// ---------------------------------------- weight transpose + bf16 hi/lo split
// z in [0,6): {w_q, w_k, w_v, w_e1_top, w_e1_bot, w_o}; Wt[n][k] = W[k][n].
__global__ __launch_bounds__(256) void conv_w(
    const float* __restrict__ w_q, const float* __restrict__ w_k,
    const float* __restrict__ w_v, const float* __restrict__ w_e1,
    const float* __restrict__ w_o, unsigned short* __restrict__ wt)
{
  __shared__ float T[32][33];
  const int z = blockIdx.z;
  const float* src = (z == 0) ? w_q : (z == 1) ? w_k : (z == 2) ? w_v
                   : (z == 3) ? w_e1 : (z == 4) ? (w_e1 + 262144) : w_o;
  unsigned short* hi = wt + (size_t)z * 524288;
  unsigned short* lo = hi + 262144;
  const int n0 = blockIdx.x * 32, k0 = blockIdx.y * 32;
  const int tx = threadIdx.x & 31, ty0 = threadIdx.x >> 5;
#pragma unroll
  for (int it = 0; it < 4; ++it) {
    const int ky = ty0 + it * 8;
    T[ky][tx] = src[(size_t)(k0 + ky) * kD + n0 + tx];
  }
  __syncthreads();
#pragma unroll
  for (int it = 0; it < 4; ++it) {
    const int ny = ty0 + it * 8;
    const float x = T[tx][ny];              // = W[k0+tx][n0+ny]
    const unsigned short h = f2bf(x);
    hi[(size_t)(n0 + ny) * kD + k0 + tx] = h;
    lo[(size_t)(n0 + ny) * kD + k0 + tx] = f2bf(x - bf2f(h));
  }
}

// ------------------------------------------------- f32 GEMM for de (direct)
// C[1024,512] = A @ W + bias. 256 thr, BM=BN=64, BK=32, reg prefetch.
__global__ __launch_bounds__(256) void gemm_f32(
    const float* __restrict__ A, const float* __restrict__ W,
    const float* __restrict__ bias, float* __restrict__ C)
{
  __shared__ float Ast[32][65];
  __shared__ float Bs[32][68];
  const int bm = blockIdx.x * 64, bn = blockIdx.y * 64;
  const int tid = threadIdx.x;
  const int ar = tid >> 2, ak = (tid & 3) * 8;
  const int bkr = tid >> 3, bn0 = (tid & 7) * 8;
  const int tx = tid & 15, ty = tid >> 4;
  const float* Ap = A + (size_t)(bm + ar) * kD + ak;
  const float* Wp = W + (size_t)bkr * kD + bn + bn0;

  float4 a0 = *reinterpret_cast<const float4*>(Ap);
  float4 a1 = *reinterpret_cast<const float4*>(Ap + 4);
  float4 b0 = *reinterpret_cast<const float4*>(Wp);
  float4 b1 = *reinterpret_cast<const float4*>(Wp + 4);

  float acc[4][4] = {};
  for (int kt = 0; kt < 16; ++kt) {
    Ast[ak + 0][ar] = a0.x; Ast[ak + 1][ar] = a0.y;
    Ast[ak + 2][ar] = a0.z; Ast[ak + 3][ar] = a0.w;
    Ast[ak + 4][ar] = a1.x; Ast[ak + 5][ar] = a1.y;
    Ast[ak + 6][ar] = a1.z; Ast[ak + 7][ar] = a1.w;
    *reinterpret_cast<float4*>(&Bs[bkr][bn0])     = b0;
    *reinterpret_cast<float4*>(&Bs[bkr][bn0 + 4]) = b1;
    __syncthreads();
    if (kt + 1 < 16) {
      const float* Ap2 = Ap + (kt + 1) * 32;
      const float* Wp2 = Wp + (size_t)(kt + 1) * 32 * kD;
      a0 = *reinterpret_cast<const float4*>(Ap2);
      a1 = *reinterpret_cast<const float4*>(Ap2 + 4);
      b0 = *reinterpret_cast<const float4*>(Wp2);
      b1 = *reinterpret_cast<const float4*>(Wp2 + 4);
    }
#pragma unroll
    for (int kk = 0; kk < 32; ++kk) {
      const float x0 = Ast[kk][ty * 4 + 0];
      const float x1 = Ast[kk][ty * 4 + 1];
      const float x2 = Ast[kk][ty * 4 + 2];
      const float x3 = Ast[kk][ty * 4 + 3];
      const float4 bv = *reinterpret_cast<const float4*>(&Bs[kk][tx * 4]);
      acc[0][0] = fmaf(x0, bv.x, acc[0][0]); acc[0][1] = fmaf(x0, bv.y, acc[0][1]);
      acc[0][2] = fmaf(x0, bv.z, acc[0][2]); acc[0][3] = fmaf(x0, bv.w, acc[0][3]);
      acc[1][0] = fmaf(x1, bv.x, acc[1][0]); acc[1][1] = fmaf(x1, bv.y, acc[1][1]);
      acc[1][2] = fmaf(x1, bv.z, acc[1][2]); acc[1][3] = fmaf(x1, bv.w, acc[1][3]);
      acc[2][0] = fmaf(x2, bv.x, acc[2][0]); acc[2][1] = fmaf(x2, bv.y, acc[2][1]);
      acc[2][2] = fmaf(x2, bv.z, acc[2][2]); acc[2][3] = fmaf(x2, bv.w, acc[2][3]);
      acc[3][0] = fmaf(x3, bv.x, acc[3][0]); acc[3][1] = fmaf(x3, bv.y, acc[3][1]);
      acc[3][2] = fmaf(x3, bv.z, acc[3][2]); acc[3][3] = fmaf(x3, bv.w, acc[3][3]);
    }
    __syncthreads();
  }
#pragma unroll
  for (int i = 0; i < 4; ++i) {
    const int row = bm + ty * 4 + i;
#pragma unroll
    for (int j = 0; j < 4; ++j) {
      const int col = bn + tx * 4 + j;
      C[(size_t)row * kD + col] = acc[i][j] + bias[col];
    }
  }
}

// ----------------------------------------------- MFMA bf16-split GEMM (3-pass)
// C[M,512] = A[M,512](f32, converted on the fly) @ Wt(hi/lo, pre-transposed).
// 64x64 tile, 4 waves (2x2 of 32x32), 16x16x32 bf16 MFMA, LDS rows padded
// to 40 bf16 (80B) -> <=2-way bank aliasing (free).
struct MJob { const float* A; const unsigned short* Wh; const unsigned short* Wl;
              const float* bias; float* C; int M; };
struct MJobs { MJob j[3]; };

__global__ __launch_bounds__(256) void gemm_mfma(
    MJobs jobs, int zNorms,
    const float* __restrict__ deN, const float* __restrict__ nvN,
    float* __restrict__ invde, float* __restrict__ invvar)
{
  if ((int)blockIdx.z == zNorms) {
    // row inverse norms: flat block over (x,y); 4 waves x 4 rows = 16 rows
    const int flat = blockIdx.x + gridDim.x * blockIdx.y;
    const int lane = threadIdx.x & 63;
    const int w = threadIdx.x >> 6;
#pragma unroll
    for (int r = 0; r < 4; ++r) {
      const int wid = flat * 16 + w * 4 + r;
      if (wid >= 2 * kB * kN) break;
      const float* row;
      if (wid < kB * kN) {
        row = deN + (size_t)wid * kD;
      } else {
        const int t = wid - kB * kN;
        row = nvN + ((size_t)(t / kN) * kS + 1 + (t % kN)) * kD;
      }
      const float4* r4 = reinterpret_cast<const float4*>(row) + lane * 2;
      const float4 x0 = r4[0], x1 = r4[1];
      float ss = x0.x * x0.x + x0.y * x0.y + x0.z * x0.z + x0.w * x0.w
               + x1.x * x1.x + x1.y * x1.y + x1.z * x1.z + x1.w * x1.w;
      ss = wsum(ss);
      if (lane == 0) {
        const float inv = 1.f / sqrtf(ss);
        if (wid < kB * kN) invde[wid] = inv; else invvar[wid - kB * kN] = inv;
      }
    }
    return;
  }

  const MJob jb = jobs.j[blockIdx.z];
  __shared__ unsigned short Ah[64][40], Al[64][40], Wh[64][40], Wl[64][40];
  const int tid = threadIdx.x;
  const int lane = tid & 63, wv = tid >> 6;
  const int wr = wv >> 1, wc = wv & 1;
  const int bm = blockIdx.x * 64, bn = blockIdx.y * 64;
  const int sr = tid >> 2, sk = (tid & 3) * 8;      // staging: row, k-offset
  const bool aok = (bm + sr) < jb.M;
  const float* Ap = jb.A + (size_t)(bm + sr) * kD + sk;
  const unsigned short* Whp = jb.Wh + (size_t)(bn + sr) * kD + sk;
  const unsigned short* Wlp = jb.Wl + (size_t)(bn + sr) * kD + sk;

  const f32x4 zero = {0.f, 0.f, 0.f, 0.f};
  f32x4 acc00 = zero, acc01 = zero, acc10 = zero, acc11 = zero;

  for (int k0 = 0; k0 < kD; k0 += 32) {
    float4 a0 = {0.f, 0.f, 0.f, 0.f}, a1 = {0.f, 0.f, 0.f, 0.f};
    if (aok) {
      a0 = *reinterpret_cast<const float4*>(Ap + k0);
      a1 = *reinterpret_cast<const float4*>(Ap + k0 + 4);
    }
    const uint4 wh4 = *reinterpret_cast<const uint4*>(Whp + k0);
    const uint4 wl4 = *reinterpret_cast<const uint4*>(Wlp + k0);
    const float av[8] = {a0.x, a0.y, a0.z, a0.w, a1.x, a1.y, a1.z, a1.w};
    unsigned short h[8], l[8];
#pragma unroll
    for (int e = 0; e < 8; ++e) {
      h[e] = f2bf(av[e]);
      l[e] = f2bf(av[e] - bf2f(h[e]));
    }
    const uint4 hp = { pk2(h[0], h[1]), pk2(h[2], h[3]), pk2(h[4], h[5]), pk2(h[6], h[7]) };
    const uint4 lp = { pk2(l[0], l[1]), pk2(l[2], l[3]), pk2(l[4], l[5]), pk2(l[6], l[7]) };
    *reinterpret_cast<uint4*>(&Ah[sr][sk]) = hp;
    *reinterpret_cast<uint4*>(&Al[sr][sk]) = lp;
    *reinterpret_cast<uint4*>(&Wh[sr][sk]) = wh4;
    *reinterpret_cast<uint4*>(&Wl[sr][sk]) = wl4;
    __syncthreads();

    const int fr = lane & 15, kg = lane >> 4;
#pragma unroll
    for (int fm = 0; fm < 2; ++fm) {
      const int arow = wr * 32 + fm * 16 + fr;
      const bf16x8 amh = *reinterpret_cast<const bf16x8*>(&Ah[arow][kg * 8]);
      const bf16x8 aml = *reinterpret_cast<const bf16x8*>(&Al[arow][kg * 8]);
#pragma unroll
      for (int fn = 0; fn < 2; ++fn) {
        const int wrow = wc * 32 + fn * 16 + fr;
        const bf16x8 bh = *reinterpret_cast<const bf16x8*>(&Wh[wrow][kg * 8]);
        const bf16x8 bl = *reinterpret_cast<const bf16x8*>(&Wl[wrow][kg * 8]);
        f32x4 acc = (fm == 0) ? (fn == 0 ? acc00 : acc01) : (fn == 0 ? acc10 : acc11);
        acc = __builtin_amdgcn_mfma_f32_16x16x32_bf16(amh, bh, acc, 0, 0, 0);
        acc = __builtin_amdgcn_mfma_f32_16x16x32_bf16(amh, bl, acc, 0, 0, 0);
        acc = __builtin_amdgcn_mfma_f32_16x16x32_bf16(aml, bh, acc, 0, 0, 0);
        if (fm == 0) { if (fn == 0) acc00 = acc; else acc01 = acc; }
        else         { if (fn == 0) acc10 = acc; else acc11 = acc; }
      }
    }
    __syncthreads();
  }

  // epilogue: D col = lane&15, row = (lane>>4)*4 + e  [m89-verified]
  const int rg = lane >> 4, cc = lane & 15;
#pragma unroll
  for (int fm = 0; fm < 2; ++fm) {
#pragma unroll
    for (int fn = 0; fn < 2; ++fn) {
      const f32x4 acc = (fm == 0) ? (fn == 0 ? acc00 : acc01) : (fn == 0 ? acc10 : acc11);
      const int row0 = bm + wr * 32 + fm * 16 + rg * 4;
      const int col  = bn + wc * 32 + fn * 16 + cc;
      const float bb = jb.bias ? jb.bias[col] : 0.f;
#pragma unroll
      for (int e = 0; e < 4; ++e) {
        const int row = row0 + e;
        if (row < jb.M) jb.C[(size_t)row * kD + col] = acc[e] + bb;
      }
    }
  }
}

// ------------------------------------------- fused: adjacency + qk + w2eff
__global__ __launch_bounds__(512) void graph_prep(
    const float* __restrict__ de, const float* __restrict__ nv,
    const float* __restrict__ invde, const float* __restrict__ invvar,
    const float* __restrict__ topo_p, float* __restrict__ adj,
    const float* __restrict__ q, const float* __restrict__ k,
    const float* __restrict__ w_attn,
    float* __restrict__ sq, float* __restrict__ sk,
    const float* __restrict__ w_edge2, const float* __restrict__ b_edge2,
    float* __restrict__ w2eff, float* __restrict__ b2eff)
{
  const int blk = blockIdx.x;
  if (blk < kB * kN) {
    __shared__ float lg[kN];
    const int b = blk >> 6, i = blk & 63;
    const int w = threadIdx.x >> 6, lane = threadIdx.x & 63;
    const int p = lane & 7, oct = lane >> 3;
    const int j = w * 8 + p;
    const float topo = topo_p[0];
    const float4* di = reinterpret_cast<const float4*>(de + ((size_t)b * kN + i) * kD + oct * 64);
    const float4* dj = reinterpret_cast<const float4*>(de + ((size_t)b * kN + j) * kD + oct * 64);
    const float4* vi = reinterpret_cast<const float4*>(nv + ((size_t)b * kS + 1 + i) * kD + oct * 64);
    const float4* vj = reinterpret_cast<const float4*>(nv + ((size_t)b * kS + 1 + j) * kD + oct * 64);
    float g = 0.f, sv = 0.f;
#pragma unroll
    for (int t = 0; t < 16; ++t) {
      const float4 a = di[t], c = dj[t];
      g += a.x * c.x + a.y * c.y + a.z * c.z + a.w * c.w;
      const float4 x = vi[t], y = vj[t];
      sv += x.x * y.x + x.y * y.y + x.z * y.z + x.w * y.w;
    }
    g = osum(g);
    sv = osum(sv);
    if (oct == 0) {
      const float gs = g * invde[b * kN + i] * invde[b * kN + j] + topo;
      const bool hard = (gs > 0.f) && (j != i);   // sigmoid(x)>0.5 <=> x>0
      lg[j] = hard ? sv * invvar[b * kN + i] * invvar[b * kN + j] : 0.f;
    }
    __syncthreads();
    if (threadIdx.x < 64) {
      const float x = lg[lane];
      const float m = wmax(x);
      const float e = expf(x - m);
      const float s = wsum(e);
      adj[((size_t)b * kN + i) * kN + lane] = e / s;
    }
    return;
  }
  if (blk < kB * kN + 33) {
    const int t = (blk - kB * kN) * 512 + threadIdx.x;
    const int total = kB * kS * kH;
    if (t >= 2 * total) return;
    const int which = (t >= total) ? 1 : 0;
    const int r = which ? t - total : t;
    const int h = r % kH, bs = r / kH;
    const float* src = which ? k : q;
    const float* wa = w_attn + which * kHD;
    const float4* row = reinterpret_cast<const float4*>(src + (size_t)bs * kD + h * kHD);
    const float4* w4 = reinterpret_cast<const float4*>(wa);
    float acc = 0.f;
#pragma unroll
    for (int c = 0; c < kHD / 4; ++c) {
      const float4 a = row[c], w = w4[c];
      acc += a.x * w.x + a.y * w.y + a.z * w.z + a.w * w.w;
    }
    (which ? sk : sq)[r] = acc;
    return;
  }
  {
    const int t = (blk - kB * kN - 33) * 512 + threadIdx.x;
    if (t >= (kD + 1) * kH) return;
    const int c = t >> 3, h = t & 7;
    const float* src = (c < kD) ? (w_edge2 + (size_t)c * kD + h * kHD)
                                : (b_edge2 + h * kHD);
    const float4* s4 = reinterpret_cast<const float4*>(src);
    const float4* wa4 = reinterpret_cast<const float4*>(w_attn + 2 * kHD);
    float acc = 0.f;
#pragma unroll
    for (int u = 0; u < kHD / 4; ++u) {
      const float4 a = s4[u], w = wa4[u];
      acc += a.x * w.x + a.y * w.y + a.z * w.z + a.w * w.w;
    }
    if (c < kD) w2eff[c * kH + h] = acc; else b2eff[h] = acc;
  }
}

// -------------------------------------------------------------- edge scores
__global__ __launch_bounds__(256) void edge_scores(
    const float* __restrict__ Pp, const float* __restrict__ Qq,
    const float* __restrict__ gamma, const float* __restrict__ beta,
    const float* __restrict__ w2eff, const float* __restrict__ b2eff,
    float* __restrict__ es)
{
  const int wid = blockIdx.x * 4 + (threadIdx.x >> 6);
  const int lane = threadIdx.x & 63;
  const int p = lane & 7, oct = lane >> 3;
  const int pair = wid * 8 + p;                      // 0 .. B*S*N-1
  const int b = pair / (kS * kN);
  const int r = pair % (kS * kN);
  const int i = r / kN, jj = r % kN;                 // j = jj+1
  const int prow = b * kN + (i == 0 ? jj : i - 1);
  const int qrow = b * kN + jj;
  const int c0 = oct * 64;
  const float4* Pr = reinterpret_cast<const float4*>(Pp + (size_t)prow * kD + c0);
  const float4* Qr = reinterpret_cast<const float4*>(Qq + (size_t)qrow * kD + c0);

  float4 z4[16];
  float s1 = 0.f, s2 = 0.f;
#pragma unroll
  for (int t = 0; t < 16; ++t) {
    const float4 a = Pr[t], c = Qr[t];
    float4 z;
    z.x = a.x + c.x; z.y = a.y + c.y; z.z = a.z + c.z; z.w = a.w + c.w;
    z4[t] = z;
    s1 += (z.x + z.y) + (z.z + z.w);
    s2 += (z.x * z.x + z.y * z.y) + (z.z * z.z + z.w * z.w);
  }
  s1 = osum(s1);
  s2 = osum(s2);
  const float mu = s1 * (1.f / kD);
  const float var = s2 * (1.f / kD) - mu * mu;
  const float rstd = rsqrtf(var + 1e-5f);
  const float nb = -mu * rstd;

  float acc[8] = {};
#pragma unroll
  for (int t = 0; t < 16; ++t) {
    const float4 g4 = *reinterpret_cast<const float4*>(gamma + c0 + t * 4);
    const float4 b4 = *reinterpret_cast<const float4*>(beta + c0 + t * 4);
    const float zc[4] = { z4[t].x, z4[t].y, z4[t].z, z4[t].w };
    const float gc[4] = { g4.x, g4.y, g4.z, g4.w };
    const float bc[4] = { b4.x, b4.y, b4.z, b4.w };
#pragma unroll
    for (int u = 0; u < 4; ++u) {
      const float zn = fmaf(zc[u], rstd, nb);
      const float eu = fmaxf(fmaf(zn, gc[u], bc[u]), 0.f);
      const float4* w4 = reinterpret_cast<const float4*>(w2eff + (size_t)(c0 + t * 4 + u) * kH);
      const float4 wa = w4[0], wb = w4[1];
      acc[0] = fmaf(eu, wa.x, acc[0]); acc[1] = fmaf(eu, wa.y, acc[1]);
      acc[2] = fmaf(eu, wa.z, acc[2]); acc[3] = fmaf(eu, wa.w, acc[3]);
      acc[4] = fmaf(eu, wb.x, acc[4]); acc[5] = fmaf(eu, wb.y, acc[5]);
      acc[6] = fmaf(eu, wb.z, acc[6]); acc[7] = fmaf(eu, wb.w, acc[7]);
    }
  }
#pragma unroll
  for (int h = 0; h < 8; ++h) acc[h] = osum(acc[h]);
  if (oct == 0) {
    const float4 ba0 = *reinterpret_cast<const float4*>(b2eff);
    const float4 ba1 = *reinterpret_cast<const float4*>(b2eff + 4);
    float* dst = es + (((size_t)b * kS + i) * kS + jj + 1) * kH;
    float4 o0, o1;
    o0.x = acc[0] + ba0.x; o0.y = acc[1] + ba0.y; o0.z = acc[2] + ba0.z; o0.w = acc[3] + ba0.w;
    o1.x = acc[4] + ba1.x; o1.y = acc[5] + ba1.y; o1.z = acc[6] + ba1.z; o1.w = acc[7] + ba1.w;
    reinterpret_cast<float4*>(dst)[0] = o0;
    reinterpret_cast<float4*>(dst)[1] = o1;
  }
}

// --------------------------------------------- attn softmax + context rows
__global__ __launch_bounds__(576) void attn_ctx(
    const float* __restrict__ sq, const float* __restrict__ sk,
    const float* __restrict__ es, const float* __restrict__ adj,
    const float* __restrict__ v, const float* __restrict__ b_attn,
    float* __restrict__ attn_out, float* __restrict__ ctx)
{
  __shared__ float prob[kH][kS];
  const int bi = blockIdx.x;
  const int b = bi / kS, i = bi % kS;
  const int tid = threadIdx.x;
  const float ba = b_attn[0];
  if (tid < kH * kS) {
    const int h = tid / kS, j = tid % kS;
    float lgv;
    if (j == 0) {
      lgv = -1e30f;
    } else {
      const float a = (i == 0) ? 1.f : adj[((size_t)b * kN + (i - 1)) * kN + (j - 1)];
      lgv = sq[(b * kS + i) * kH + h] + sk[(b * kS + j) * kH + h]
          + es[(((size_t)b * kS + i) * kS + j) * kH + h] * a + ba;
    }
    prob[h][j] = lgv;
  }
  __syncthreads();
  const int w = tid >> 6, lane = tid & 63;
  if (w < kH) {
    const float x = prob[w][lane];
    const float xe = prob[w][64];
    float m = wmax(x);
    m = fmaxf(m, xe);
    const float e = expf(x - m);
    const float ee = expf(xe - m);
    const float s = wsum(e) + ee;
    const float inv = 1.f / s;
    prob[w][lane] = e * inv;
    if (lane == 0) prob[w][64] = ee * inv;
  }
  __syncthreads();
  if (tid < kH * kS) {
    const int h = tid / kS, j = tid % kS;
    attn_out[(((size_t)b * kH + h) * kS + i) * kS + j] = prob[h][j];
  }
  if (tid < kD) {
    const int h = tid >> 6, d = tid & 63;
    const float* vb = v + (size_t)b * kS * kD + h * kHD + d;
    float a0 = 0.f, a1 = 0.f, a2 = 0.f, a3 = 0.f;
#pragma unroll 4
    for (int j = 1; j < kS; j += 4) {
      a0 = fmaf(prob[h][j + 0], vb[(size_t)(j + 0) * kD], a0);
      a1 = fmaf(prob[h][j + 1], vb[(size_t)(j + 1) * kD], a1);
      a2 = fmaf(prob[h][j + 2], vb[(size_t)(j + 2) * kD], a2);
      a3 = fmaf(prob[h][j + 3], vb[(size_t)(j + 3) * kD], a3);
    }
    ctx[((size_t)b * kS + i) * kD + tid] = (a0 + a1) + (a2 + a3);
  }
}

// ---------------------------------------------------------------- launcher
extern "C" void kernel_launch(void* const* d_in, const int* in_sizes, int n_in,
                              void* d_out, int out_size, void* d_ws, size_t ws_size,
                              hipStream_t stream)
{
  const float* desc = (const float*)d_in[0];
  const float* nv   = (const float*)d_in[1];
  const float* w_gt = (const float*)d_in[2];
  const float* b_gt = (const float*)d_in[3];
  const float* topo = (const float*)d_in[4];
  const float* w_e1 = (const float*)d_in[5];
  const float* b_e1 = (const float*)d_in[6];
  const float* ln_g = (const float*)d_in[7];
  const float* ln_b = (const float*)d_in[8];
  const float* w_e2 = (const float*)d_in[9];
  const float* b_e2 = (const float*)d_in[10];
  const float* w_q  = (const float*)d_in[11];
  const float* b_q  = (const float*)d_in[12];
  const float* w_k  = (const float*)d_in[13];
  const float* b_k  = (const float*)d_in[14];
  const float* w_v  = (const float*)d_in[15];
  const float* b_v  = (const float*)d_in[16];
  const float* w_at = (const float*)d_in[17];
  const float* b_at = (const float*)d_in[18];
  const float* w_o  = (const float*)d_in[19];
  const float* b_o  = (const float*)d_in[20];

  float* ws  = (float*)d_ws;
  float* de  = ws;                    // B*N*D
  float* q   = de  + 524288;          // B*S*D
  float* k   = q   + 532480;
  float* v   = k   + 532480;
  float* Pp  = v   + 532480;          // B*N*D
  float* Qq  = Pp  + 524288;
  float* adj = Qq  + 524288;          // B*N*N
  float* sq  = adj + 65536;           // B*S*H
  float* sk  = sq  + 8320;
  float* es  = sk  + 8320;            // B*S*S*H
  float* ctx = es  + 540800;          // B*S*D
  float* w2e = ctx + 532480;          // D*H
  float* b2e = w2e + 4096;            // H
  float* ivd = b2e + 8;               // B*N
  float* ivv = ivd + 1024;            // B*N
  unsigned short* wt = (unsigned short*)(ivv + 1024);   // 6 x (hi 256K + lo 256K) ushort

  float* out  = (float*)d_out;                 // (B,S,D)
  float* attn = out + (size_t)kB * kS * kD;    // (B,H,S,S)

  // D0: weight transpose + bf16 hi/lo conversion (wq,wk,wv,we1a,we1b,wo)
  conv_w<<<dim3(16, 16, 6), 256, 0, stream>>>(w_q, w_k, w_v, w_e1, w_o, wt);
  // D1: de = desc @ w_gt + b (f32, threshold-safe)
  gemm_f32<<<dim3(16, 8), 256, 0, stream>>>(desc, w_gt, b_gt, de);
  // D2: q,k,v via MFMA bf16-split
  {
    MJobs jobs;
    jobs.j[0] = { nv, wt + 0u * 524288, wt + 0u * 524288 + 262144, b_q, q, kB * kS };
    jobs.j[1] = { nv, wt + 1u * 524288, wt + 1u * 524288 + 262144, b_k, k, kB * kS };
    jobs.j[2] = { nv, wt + 2u * 524288, wt + 2u * 524288 + 262144, b_v, v, kB * kS };
    gemm_mfma<<<dim3(17, 8, 3), 256, 0, stream>>>(jobs, -1, nullptr, nullptr, nullptr, nullptr);
  }
  // D3: P,Q via MFMA + norms as z=2 slice (128 blocks x 16 rows = 2048 rows)
  {
    MJobs jobs;
    jobs.j[0] = { de, wt + 3u * 524288, wt + 3u * 524288 + 262144, b_e1,   Pp, kB * kN };
    jobs.j[1] = { de, wt + 4u * 524288, wt + 4u * 524288 + 262144, nullptr, Qq, kB * kN };
    jobs.j[2] = jobs.j[0];
    gemm_mfma<<<dim3(16, 8, 3), 256, 0, stream>>>(jobs, 2, de, nv, ivd, ivv);
  }
  // D4: adjacency (1024) + qk scores (33) + w2eff fold (9)
  graph_prep<<<1066, 512, 0, stream>>>(de, nv, ivd, ivv, topo, adj,
                                       q, k, w_at, sq, sk,
                                       w_e2, b_e2, w2e, b2e);
  // D5: edge scores
  edge_scores<<<2080, 256, 0, stream>>>(Pp, Qq, ln_g, ln_b, w2e, b2e, es);
  // D6: attention softmax + context
  attn_ctx<<<kB * kS, 576, 0, stream>>>(sq, sk, es, adj, v, b_at, attn, ctx);
  // D7: output projection via MFMA
  {
    MJobs jobs;
    jobs.j[0] = { ctx, wt + 5u * 524288, wt + 5u * 524288 + 262144, b_o, out, kB * kS };
    jobs.j[1] = jobs.j[0]; jobs.j[2] = jobs.j[0];
    gemm_mfma<<<dim3(17, 8, 1), 256, 0, stream>>>(jobs, -1, nullptr, nullptr, nullptr, nullptr);
  }
}

// Round 12
// 300.603 us; speedup vs baseline: 1.5915x; 1.0496x over previous
//
#include <hip/hip_runtime.h>
#include <math.h>

// AdaptiveGraphAttention — MI355X, round 12 (= round-11 kernel, resubmitted
// verbatim after GPU acquisition timeout; re-audited, no defects found).
// R10 measured: MFMA GEMMs landed (315us); top = edge_scores 77us @ VALUBusy
// 12.6%, Occ 27% (VGPR 76), 1GB w2eff L1 traffic, 512 head-dot FMA/lane.
// This round: (a) edge_scores v3 — the 512x8 head-dot as MFMA: wave = 16
// pairs, 2-pass LN (no z[16] regs), eu->bf16 hi/lo A-frags, pre-transposed
// padded bf16 w2p B-frags, 3 independent MFMA acc chains. (b) de joins the
// MFMA GEMM dispatch (threshold flips damped to ~4e-7); gemm_f32 gone.

constexpr int kD  = 512;
constexpr int kH  = 8;
constexpr int kHD = 64;
constexpr int kB  = 16;
constexpr int kN  = 64;
constexpr int kS  = 65;

typedef short bf16x8 __attribute__((ext_vector_type(8)));   // 8 bf16 bit-patterns
typedef float f32x4  __attribute__((ext_vector_type(4)));

__device__ __forceinline__ float wsum(float x) {
#pragma unroll
  for (int m = 1; m < 64; m <<= 1) x += __shfl_xor(x, m, 64);
  return x;
}
__device__ __forceinline__ float wmax(float x) {
#pragma unroll
  for (int m = 1; m < 64; m <<= 1) x = fmaxf(x, __shfl_xor(x, m, 64));
  return x;
}
__device__ __forceinline__ float osum(float x) {
  x += __shfl_xor(x, 8, 64);
  x += __shfl_xor(x, 16, 64);
  x += __shfl_xor(x, 32, 64);
  return x;
}

__device__ __forceinline__ unsigned short f2bf(float x) {   // RNE f32->bf16
  unsigned int u = __builtin_bit_cast(unsigned int, x);
  u += 0x7FFFu + ((u >> 16) & 1u);
  return (unsigned short)(u >> 16);
}
__device__ __forceinline__ float bf2f(unsigned short h) {
  return __builtin_bit_cast(float, ((unsigned int)h) << 16);
}
__device__ __forceinline__ unsigned int pk2(unsigned short a, unsigned short b) {
  return (unsigned int)a | ((unsigned int)b << 16);
}

// ---------------------------------------- weight transpose + bf16 hi/lo split
// z in [0,7): {w_q, w_k, w_v, w_e1_top, w_e1_bot, w_o, w_gt}; Wt[n][k] = W[k][n].
__global__ __launch_bounds__(256) void conv_w(
    const float* __restrict__ w_q, const float* __restrict__ w_k,
    const float* __restrict__ w_v, const float* __restrict__ w_e1,
    const float* __restrict__ w_o, const float* __restrict__ w_gt,
    unsigned short* __restrict__ wt)
{
  __shared__ float T[32][33];
  const int z = blockIdx.z;
  const float* src = (z == 0) ? w_q : (z == 1) ? w_k : (z == 2) ? w_v
                   : (z == 3) ? w_e1 : (z == 4) ? (w_e1 + 262144)
                   : (z == 5) ? w_o : w_gt;
  unsigned short* hi = wt + (size_t)z * 524288;
  unsigned short* lo = hi + 262144;
  const int n0 = blockIdx.x * 32, k0 = blockIdx.y * 32;
  const int tx = threadIdx.x & 31, ty0 = threadIdx.x >> 5;
#pragma unroll
  for (int it = 0; it < 4; ++it) {
    const int ky = ty0 + it * 8;
    T[ky][tx] = src[(size_t)(k0 + ky) * kD + n0 + tx];
  }
  __syncthreads();
#pragma unroll
  for (int it = 0; it < 4; ++it) {
    const int ny = ty0 + it * 8;
    const float x = T[tx][ny];              // = W[k0+tx][n0+ny]
    const unsigned short h = f2bf(x);
    hi[(size_t)(n0 + ny) * kD + k0 + tx] = h;
    lo[(size_t)(n0 + ny) * kD + k0 + tx] = f2bf(x - bf2f(h));
  }
}

// ----------------------------------------------- MFMA bf16-split GEMM (3-pass)
// C[M,512] = A[M,512](f32, converted on the fly) @ Wt(hi/lo, pre-transposed).
// 64x64 tile, 4 waves (2x2 of 32x32), 16x16x32 bf16 MFMA. [HW-validated R10]
struct MJob { const float* A; const unsigned short* Wh; const unsigned short* Wl;
              const float* bias; float* C; int M; };
struct MJobs { MJob j[4]; };

__global__ __launch_bounds__(256) void gemm_mfma(
    MJobs jobs, int zNorms,
    const float* __restrict__ deN, const float* __restrict__ nvN,
    float* __restrict__ invde, float* __restrict__ invvar)
{
  if ((int)blockIdx.z == zNorms) {
    // row inverse norms: flat block over (x,y); 4 waves x 4 rows = 16 rows
    const int flat = blockIdx.x + gridDim.x * blockIdx.y;
    const int lane = threadIdx.x & 63;
    const int w = threadIdx.x >> 6;
#pragma unroll
    for (int r = 0; r < 4; ++r) {
      const int wid = flat * 16 + w * 4 + r;
      if (wid >= 2 * kB * kN) break;
      const float* row;
      if (wid < kB * kN) {
        row = deN + (size_t)wid * kD;
      } else {
        const int t = wid - kB * kN;
        row = nvN + ((size_t)(t / kN) * kS + 1 + (t % kN)) * kD;
      }
      const float4* r4 = reinterpret_cast<const float4*>(row) + lane * 2;
      const float4 x0 = r4[0], x1 = r4[1];
      float ss = x0.x * x0.x + x0.y * x0.y + x0.z * x0.z + x0.w * x0.w
               + x1.x * x1.x + x1.y * x1.y + x1.z * x1.z + x1.w * x1.w;
      ss = wsum(ss);
      if (lane == 0) {
        const float inv = 1.f / sqrtf(ss);
        if (wid < kB * kN) invde[wid] = inv; else invvar[wid - kB * kN] = inv;
      }
    }
    return;
  }

  const MJob jb = jobs.j[blockIdx.z];
  __shared__ unsigned short Ah[64][40], Al[64][40], Wh[64][40], Wl[64][40];
  const int tid = threadIdx.x;
  const int lane = tid & 63, wv = tid >> 6;
  const int wr = wv >> 1, wc = wv & 1;
  const int bm = blockIdx.x * 64, bn = blockIdx.y * 64;
  const int sr = tid >> 2, sk = (tid & 3) * 8;      // staging: row, k-offset
  const bool aok = (bm + sr) < jb.M;
  const float* Ap = jb.A + (size_t)(bm + sr) * kD + sk;
  const unsigned short* Whp = jb.Wh + (size_t)(bn + sr) * kD + sk;
  const unsigned short* Wlp = jb.Wl + (size_t)(bn + sr) * kD + sk;

  const f32x4 zero = {0.f, 0.f, 0.f, 0.f};
  f32x4 acc00 = zero, acc01 = zero, acc10 = zero, acc11 = zero;

  for (int k0 = 0; k0 < kD; k0 += 32) {
    float4 a0 = {0.f, 0.f, 0.f, 0.f}, a1 = {0.f, 0.f, 0.f, 0.f};
    if (aok) {
      a0 = *reinterpret_cast<const float4*>(Ap + k0);
      a1 = *reinterpret_cast<const float4*>(Ap + k0 + 4);
    }
    const uint4 wh4 = *reinterpret_cast<const uint4*>(Whp + k0);
    const uint4 wl4 = *reinterpret_cast<const uint4*>(Wlp + k0);
    const float av[8] = {a0.x, a0.y, a0.z, a0.w, a1.x, a1.y, a1.z, a1.w};
    unsigned short h[8], l[8];
#pragma unroll
    for (int e = 0; e < 8; ++e) {
      h[e] = f2bf(av[e]);
      l[e] = f2bf(av[e] - bf2f(h[e]));
    }
    const uint4 hp = { pk2(h[0], h[1]), pk2(h[2], h[3]), pk2(h[4], h[5]), pk2(h[6], h[7]) };
    const uint4 lp = { pk2(l[0], l[1]), pk2(l[2], l[3]), pk2(l[4], l[5]), pk2(l[6], l[7]) };
    *reinterpret_cast<uint4*>(&Ah[sr][sk]) = hp;
    *reinterpret_cast<uint4*>(&Al[sr][sk]) = lp;
    *reinterpret_cast<uint4*>(&Wh[sr][sk]) = wh4;
    *reinterpret_cast<uint4*>(&Wl[sr][sk]) = wl4;
    __syncthreads();

    const int fr = lane & 15, kg = lane >> 4;
#pragma unroll
    for (int fm = 0; fm < 2; ++fm) {
      const int arow = wr * 32 + fm * 16 + fr;
      const bf16x8 amh = *reinterpret_cast<const bf16x8*>(&Ah[arow][kg * 8]);
      const bf16x8 aml = *reinterpret_cast<const bf16x8*>(&Al[arow][kg * 8]);
#pragma unroll
      for (int fn = 0; fn < 2; ++fn) {
        const int wrow = wc * 32 + fn * 16 + fr;
        const bf16x8 bh = *reinterpret_cast<const bf16x8*>(&Wh[wrow][kg * 8]);
        const bf16x8 bl = *reinterpret_cast<const bf16x8*>(&Wl[wrow][kg * 8]);
        f32x4 acc = (fm == 0) ? (fn == 0 ? acc00 : acc01) : (fn == 0 ? acc10 : acc11);
        acc = __builtin_amdgcn_mfma_f32_16x16x32_bf16(amh, bh, acc, 0, 0, 0);
        acc = __builtin_amdgcn_mfma_f32_16x16x32_bf16(amh, bl, acc, 0, 0, 0);
        acc = __builtin_amdgcn_mfma_f32_16x16x32_bf16(aml, bh, acc, 0, 0, 0);
        if (fm == 0) { if (fn == 0) acc00 = acc; else acc01 = acc; }
        else         { if (fn == 0) acc10 = acc; else acc11 = acc; }
      }
    }
    __syncthreads();
  }

  // epilogue: D col = lane&15, row = (lane>>4)*4 + e  [HW-validated R10]
  const int rg = lane >> 4, cc = lane & 15;
#pragma unroll
  for (int fm = 0; fm < 2; ++fm) {
#pragma unroll
    for (int fn = 0; fn < 2; ++fn) {
      const f32x4 acc = (fm == 0) ? (fn == 0 ? acc00 : acc01) : (fn == 0 ? acc10 : acc11);
      const int row0 = bm + wr * 32 + fm * 16 + rg * 4;
      const int col  = bn + wc * 32 + fn * 16 + cc;
      const float bb = jb.bias ? jb.bias[col] : 0.f;
#pragma unroll
      for (int e = 0; e < 4; ++e) {
        const int row = row0 + e;
        if (row < jb.M) jb.C[(size_t)row * kD + col] = acc[e] + bb;
      }
    }
  }
}

// ------------------------------------------- fused: adjacency + qk + w2p prep
__global__ __launch_bounds__(512) void graph_prep(
    const float* __restrict__ de, const float* __restrict__ nv,
    const float* __restrict__ invde, const float* __restrict__ invvar,
    const float* __restrict__ topo_p, float* __restrict__ adj,
    const float* __restrict__ q, const float* __restrict__ k,
    const float* __restrict__ w_attn,
    float* __restrict__ sq, float* __restrict__ sk,
    const float* __restrict__ w_edge2, const float* __restrict__ b_edge2,
    unsigned short* __restrict__ w2ph, unsigned short* __restrict__ w2pl,
    float* __restrict__ b2eff)
{
  const int blk = blockIdx.x;
  if (blk < kB * kN) {
    __shared__ float lg[kN];
    const int b = blk >> 6, i = blk & 63;
    const int w = threadIdx.x >> 6, lane = threadIdx.x & 63;
    const int p = lane & 7, oct = lane >> 3;
    const int j = w * 8 + p;
    const float topo = topo_p[0];
    const float4* di = reinterpret_cast<const float4*>(de + ((size_t)b * kN + i) * kD + oct * 64);
    const float4* dj = reinterpret_cast<const float4*>(de + ((size_t)b * kN + j) * kD + oct * 64);
    const float4* vi = reinterpret_cast<const float4*>(nv + ((size_t)b * kS + 1 + i) * kD + oct * 64);
    const float4* vj = reinterpret_cast<const float4*>(nv + ((size_t)b * kS + 1 + j) * kD + oct * 64);
    float g = 0.f, sv = 0.f;
#pragma unroll
    for (int t = 0; t < 16; ++t) {
      const float4 a = di[t], c = dj[t];
      g += a.x * c.x + a.y * c.y + a.z * c.z + a.w * c.w;
      const float4 x = vi[t], y = vj[t];
      sv += x.x * y.x + x.y * y.y + x.z * y.z + x.w * y.w;
    }
    g = osum(g);
    sv = osum(sv);
    if (oct == 0) {
      const float gs = g * invde[b * kN + i] * invde[b * kN + j] + topo;
      const bool hard = (gs > 0.f) && (j != i);   // sigmoid(x)>0.5 <=> x>0
      lg[j] = hard ? sv * invvar[b * kN + i] * invvar[b * kN + j] : 0.f;
    }
    __syncthreads();
    if (threadIdx.x < 64) {
      const float x = lg[lane];
      const float m = wmax(x);
      const float e = expf(x - m);
      const float s = wsum(e);
      adj[((size_t)b * kN + i) * kN + lane] = e / s;
    }
    return;
  }
  if (blk < kB * kN + 33) {
    const int t = (blk - kB * kN) * 512 + threadIdx.x;
    const int total = kB * kS * kH;
    if (t >= 2 * total) return;
    const int which = (t >= total) ? 1 : 0;
    const int r = which ? t - total : t;
    const int h = r % kH, bs = r / kH;
    const float* src = which ? k : q;
    const float* wa = w_attn + which * kHD;
    const float4* row = reinterpret_cast<const float4*>(src + (size_t)bs * kD + h * kHD);
    const float4* w4 = reinterpret_cast<const float4*>(wa);
    float acc = 0.f;
#pragma unroll
    for (int c = 0; c < kHD / 4; ++c) {
      const float4 a = row[c], w = w4[c];
      acc += a.x * w.x + a.y * w.y + a.z * w.z + a.w * w.w;
    }
    (which ? sk : sq)[r] = acc;
    return;
  }
  {
    // w2p prep: w2eff[c,h] = sum_d w_edge2[c, h*64+d]*w_attn[128+d], stored
    // TRANSPOSED [h][c] as bf16 hi/lo with rows 8..16 zero-padded (MFMA B).
    const int rel = blk - (kB * kN + 33);     // 0..8
    const float4* wa4 = reinterpret_cast<const float4*>(w_attn + 2 * kHD);
    if (rel < 8) {
      const int t = rel * 512 + threadIdx.x;  // 0..4096
      const int c = t >> 3, h = t & 7;
      const float4* s4 = reinterpret_cast<const float4*>(w_edge2 + (size_t)c * kD + h * kHD);
      float acc = 0.f;
#pragma unroll
      for (int u = 0; u < kHD / 4; ++u) {
        const float4 a = s4[u], w = wa4[u];
        acc += a.x * w.x + a.y * w.y + a.z * w.z + a.w * w.w;
      }
      const unsigned short hi = f2bf(acc);
      w2ph[h * kD + c] = hi;
      w2pl[h * kD + c] = f2bf(acc - bf2f(hi));
    } else {
      if (threadIdx.x < kH) {
        const int h = threadIdx.x;
        float acc = 0.f;
        for (int d = 0; d < kHD; ++d)
          acc += b_edge2[h * kHD + d] * w_attn[2 * kHD + d];
        b2eff[h] = acc;
      }
      for (int u = threadIdx.x; u < 8 * kD; u += 512) {
        w2ph[8 * kD + u] = 0;
        w2pl[8 * kD + u] = 0;
      }
    }
  }
}

// -------------------------------------------------------------- edge scores v3
// wave = 16 consecutive pairs (same (b,i), jj = j0..j0+16). Lane(m=lane&15,
// kg=lane>>4): channels kg*8 per 32-chunk. 2-pass LN; head-dot via 3 MFMA
// chains (eu hi/lo x w2p hi). A/B/C layouts identical to gemm_mfma [HW-val].
__global__ __launch_bounds__(256) void edge_scores(
    const float* __restrict__ Pp, const float* __restrict__ Qq,
    const float* __restrict__ gamma, const float* __restrict__ beta,
    const unsigned short* __restrict__ w2ph, const unsigned short* __restrict__ w2pl,
    const float* __restrict__ b2eff, float* __restrict__ es)
{
  const int g = blockIdx.x * 4 + (threadIdx.x >> 6);   // pair-group (16 pairs)
  const int lane = threadIdx.x & 63;
  const int m = lane & 15, kg = lane >> 4;
  const int base = g * 16;
  const int b = base / (kS * kN);
  const int r0 = base % (kS * kN);
  const int i = r0 / kN, j0 = r0 % kN;                 // j0 multiple of 16
  const int jj = j0 + m;
  const int qrow = b * kN + jj;
  const int prow = (i == 0) ? qrow : (b * kN + i - 1);
  const float* Pr = Pp + (size_t)prow * kD;
  const float* Qr = Qq + (size_t)qrow * kD;

  // phase 1: LN stats; pair m's channels live in lanes {m, m+16, m+32, m+48}
  float s1 = 0.f, s2 = 0.f;
#pragma unroll 4
  for (int s = 0; s < 16; ++s) {
    const int c = s * 32 + kg * 8;
    const float4 pa = *reinterpret_cast<const float4*>(Pr + c);
    const float4 pb = *reinterpret_cast<const float4*>(Pr + c + 4);
    const float4 qa = *reinterpret_cast<const float4*>(Qr + c);
    const float4 qb = *reinterpret_cast<const float4*>(Qr + c + 4);
    const float z0 = pa.x + qa.x, z1 = pa.y + qa.y, z2 = pa.z + qa.z, z3 = pa.w + qa.w;
    const float z4 = pb.x + qb.x, z5 = pb.y + qb.y, z6 = pb.z + qb.z, z7 = pb.w + qb.w;
    s1 += ((z0 + z1) + (z2 + z3)) + ((z4 + z5) + (z6 + z7));
    s2 += ((z0 * z0 + z1 * z1) + (z2 * z2 + z3 * z3))
        + ((z4 * z4 + z5 * z5) + (z6 * z6 + z7 * z7));
  }
  s1 += __shfl_xor(s1, 16, 64); s1 += __shfl_xor(s1, 32, 64);
  s2 += __shfl_xor(s2, 16, 64); s2 += __shfl_xor(s2, 32, 64);
  const float mu = s1 * (1.f / kD);
  const float var = s2 * (1.f / kD) - mu * mu;
  const float rstd = rsqrtf(var + 1e-5f);
  const float nb = -mu * rstd;

  // phase 2: eu -> bf16 hi/lo A-frags; B-frags from w2p; 3 independent chains
  const f32x4 zero = {0.f, 0.f, 0.f, 0.f};
  f32x4 accA = zero, accB = zero, accC = zero;
#pragma unroll 4
  for (int s = 0; s < 16; ++s) {
    const int c = s * 32 + kg * 8;
    const float4 pa = *reinterpret_cast<const float4*>(Pr + c);
    const float4 pb = *reinterpret_cast<const float4*>(Pr + c + 4);
    const float4 qa = *reinterpret_cast<const float4*>(Qr + c);
    const float4 qb = *reinterpret_cast<const float4*>(Qr + c + 4);
    const float4 ga = *reinterpret_cast<const float4*>(gamma + c);
    const float4 gb = *reinterpret_cast<const float4*>(gamma + c + 4);
    const float4 ba = *reinterpret_cast<const float4*>(beta + c);
    const float4 bb = *reinterpret_cast<const float4*>(beta + c + 4);
    const float zv[8] = { pa.x + qa.x, pa.y + qa.y, pa.z + qa.z, pa.w + qa.w,
                          pb.x + qb.x, pb.y + qb.y, pb.z + qb.z, pb.w + qb.w };
    const float gv[8] = { ga.x, ga.y, ga.z, ga.w, gb.x, gb.y, gb.z, gb.w };
    const float bv[8] = { ba.x, ba.y, ba.z, ba.w, bb.x, bb.y, bb.z, bb.w };
    unsigned short h8[8], l8[8];
#pragma unroll
    for (int e = 0; e < 8; ++e) {
      const float zn = fmaf(zv[e], rstd, nb);
      const float eu = fmaxf(fmaf(zn, gv[e], bv[e]), 0.f);
      h8[e] = f2bf(eu);
      l8[e] = f2bf(eu - bf2f(h8[e]));
    }
    const uint4 hp = { pk2(h8[0], h8[1]), pk2(h8[2], h8[3]), pk2(h8[4], h8[5]), pk2(h8[6], h8[7]) };
    const uint4 lp = { pk2(l8[0], l8[1]), pk2(l8[2], l8[3]), pk2(l8[4], l8[5]), pk2(l8[6], l8[7]) };
    const bf16x8 Af_h = __builtin_bit_cast(bf16x8, hp);
    const bf16x8 Af_l = __builtin_bit_cast(bf16x8, lp);
    const bf16x8 Bh = *reinterpret_cast<const bf16x8*>(w2ph + (size_t)m * kD + c);
    const bf16x8 Bl = *reinterpret_cast<const bf16x8*>(w2pl + (size_t)m * kD + c);
    accA = __builtin_amdgcn_mfma_f32_16x16x32_bf16(Af_h, Bh, accA, 0, 0, 0);
    accB = __builtin_amdgcn_mfma_f32_16x16x32_bf16(Af_h, Bl, accB, 0, 0, 0);
    accC = __builtin_amdgcn_mfma_f32_16x16x32_bf16(Af_l, Bh, accC, 0, 0, 0);
  }

  // epilogue: D col = lane&15 (head), row = kg*4+e (pair offset)
  const int n = lane & 15;
  if (n < kH) {
    const float be = b2eff[n];
#pragma unroll
    for (int e = 0; e < 4; ++e) {
      const int mp = kg * 4 + e;
      es[(((size_t)b * kS + i) * kS + (j0 + mp + 1)) * kH + n]
          = (accA[e] + accB[e]) + accC[e] + be;
    }
  }
}

// --------------------------------------------- attn softmax + context rows
__global__ __launch_bounds__(576) void attn_ctx(
    const float* __restrict__ sq, const float* __restrict__ sk,
    const float* __restrict__ es, const float* __restrict__ adj,
    const float* __restrict__ v, const float* __restrict__ b_attn,
    float* __restrict__ attn_out, float* __restrict__ ctx)
{
  __shared__ float prob[kH][kS];
  const int bi = blockIdx.x;
  const int b = bi / kS, i = bi % kS;
  const int tid = threadIdx.x;
  const float ba = b_attn[0];
  if (tid < kH * kS) {
    const int h = tid / kS, j = tid % kS;
    float lgv;
    if (j == 0) {
      lgv = -1e30f;
    } else {
      const float a = (i == 0) ? 1.f : adj[((size_t)b * kN + (i - 1)) * kN + (j - 1)];
      lgv = sq[(b * kS + i) * kH + h] + sk[(b * kS + j) * kH + h]
          + es[(((size_t)b * kS + i) * kS + j) * kH + h] * a + ba;
    }
    prob[h][j] = lgv;
  }
  __syncthreads();
  const int w = tid >> 6, lane = tid & 63;
  if (w < kH) {
    const float x = prob[w][lane];
    const float xe = prob[w][64];
    float m = wmax(x);
    m = fmaxf(m, xe);
    const float e = expf(x - m);
    const float ee = expf(xe - m);
    const float s = wsum(e) + ee;
    const float inv = 1.f / s;
    prob[w][lane] = e * inv;
    if (lane == 0) prob[w][64] = ee * inv;
  }
  __syncthreads();
  if (tid < kH * kS) {
    const int h = tid / kS, j = tid % kS;
    attn_out[(((size_t)b * kH + h) * kS + i) * kS + j] = prob[h][j];
  }
  if (tid < kD) {
    const int h = tid >> 6, d = tid & 63;
    const float* vb = v + (size_t)b * kS * kD + h * kHD + d;
    float a0 = 0.f, a1 = 0.f, a2 = 0.f, a3 = 0.f;
#pragma unroll 4
    for (int j = 1; j < kS; j += 4) {
      a0 = fmaf(prob[h][j + 0], vb[(size_t)(j + 0) * kD], a0);
      a1 = fmaf(prob[h][j + 1], vb[(size_t)(j + 1) * kD], a1);
      a2 = fmaf(prob[h][j + 2], vb[(size_t)(j + 2) * kD], a2);
      a3 = fmaf(prob[h][j + 3], vb[(size_t)(j + 3) * kD], a3);
    }
    ctx[((size_t)b * kS + i) * kD + tid] = (a0 + a1) + (a2 + a3);
  }
}

// ---------------------------------------------------------------- launcher
extern "C" void kernel_launch(void* const* d_in, const int* in_sizes, int n_in,
                              void* d_out, int out_size, void* d_ws, size_t ws_size,
                              hipStream_t stream)
{
  const float* desc = (const float*)d_in[0];
  const float* nv   = (const float*)d_in[1];
  const float* w_gt = (const float*)d_in[2];
  const float* b_gt = (const float*)d_in[3];
  const float* topo = (const float*)d_in[4];
  const float* w_e1 = (const float*)d_in[5];
  const float* b_e1 = (const float*)d_in[6];
  const float* ln_g = (const float*)d_in[7];
  const float* ln_b = (const float*)d_in[8];
  const float* w_e2 = (const float*)d_in[9];
  const float* b_e2 = (const float*)d_in[10];
  const float* w_q  = (const float*)d_in[11];
  const float* b_q  = (const float*)d_in[12];
  const float* w_k  = (const float*)d_in[13];
  const float* b_k  = (const float*)d_in[14];
  const float* w_v  = (const float*)d_in[15];
  const float* b_v  = (const float*)d_in[16];
  const float* w_at = (const float*)d_in[17];
  const float* b_at = (const float*)d_in[18];
  const float* w_o  = (const float*)d_in[19];
  const float* b_o  = (const float*)d_in[20];

  float* ws  = (float*)d_ws;
  float* de  = ws;                    // B*N*D
  float* q   = de  + 524288;          // B*S*D
  float* k   = q   + 532480;
  float* v   = k   + 532480;
  float* Pp  = v   + 532480;          // B*N*D
  float* Qq  = Pp  + 524288;
  float* adj = Qq  + 524288;          // B*N*N
  float* sq  = adj + 65536;           // B*S*H
  float* sk  = sq  + 8320;
  float* es  = sk  + 8320;            // B*S*S*H
  float* ctx = es  + 540800;          // B*S*D
  float* b2e = ctx + 532480;          // H (+pad)
  float* ivd = b2e + 8;               // B*N
  float* ivv = ivd + 1024;            // B*N
  unsigned short* wt   = (unsigned short*)(ivv + 1024);  // 7 x (hi 256K + lo 256K)
  unsigned short* w2ph = wt + 7u * 524288;               // 16 x 512 bf16 (padded)
  unsigned short* w2pl = w2ph + 8192;

  float* out  = (float*)d_out;                 // (B,S,D)
  float* attn = out + (size_t)kB * kS * kD;    // (B,H,S,S)

  // D0: weight transpose + bf16 hi/lo conversion (wq,wk,wv,we1a,we1b,wo,wgt)
  conv_w<<<dim3(16, 16, 7), 256, 0, stream>>>(w_q, w_k, w_v, w_e1, w_o, w_gt, wt);
  // D1: de,q,k,v via MFMA bf16-split (de = job 0; threshold flips damped)
  {
    MJobs jobs;
    jobs.j[0] = { desc, wt + 6u * 524288, wt + 6u * 524288 + 262144, b_gt, de, kB * kN };
    jobs.j[1] = { nv,   wt + 0u * 524288, wt + 0u * 524288 + 262144, b_q,  q,  kB * kS };
    jobs.j[2] = { nv,   wt + 1u * 524288, wt + 1u * 524288 + 262144, b_k,  k,  kB * kS };
    jobs.j[3] = { nv,   wt + 2u * 524288, wt + 2u * 524288 + 262144, b_v,  v,  kB * kS };
    gemm_mfma<<<dim3(17, 8, 4), 256, 0, stream>>>(jobs, -1, nullptr, nullptr, nullptr, nullptr);
  }
  // D2: P,Q via MFMA + norms as z=2 slice (128 blocks x 16 rows = 2048 rows)
  {
    MJobs jobs;
    jobs.j[0] = { de, wt + 3u * 524288, wt + 3u * 524288 + 262144, b_e1,   Pp, kB * kN };
    jobs.j[1] = { de, wt + 4u * 524288, wt + 4u * 524288 + 262144, nullptr, Qq, kB * kN };
    jobs.j[2] = jobs.j[0]; jobs.j[3] = jobs.j[0];
    gemm_mfma<<<dim3(16, 8, 3), 256, 0, stream>>>(jobs, 2, de, nv, ivd, ivv);
  }
  // D3: adjacency (1024) + qk scores (33) + w2p prep (9)
  graph_prep<<<1066, 512, 0, stream>>>(de, nv, ivd, ivv, topo, adj,
                                       q, k, w_at, sq, sk,
                                       w_e2, b_e2, w2ph, w2pl, b2e);
  // D4: edge scores (MFMA head-dot): 66560 pairs / 16 per wave / 4 waves
  edge_scores<<<1040, 256, 0, stream>>>(Pp, Qq, ln_g, ln_b, w2ph, w2pl, b2e, es);
  // D5: attention softmax + context
  attn_ctx<<<kB * kS, 576, 0, stream>>>(sq, sk, es, adj, v, b_at, attn, ctx);
  // D6: output projection via MFMA
  {
    MJobs jobs;
    jobs.j[0] = { ctx, wt + 5u * 524288, wt + 5u * 524288 + 262144, b_o, out, kB * kS };
    jobs.j[1] = jobs.j[0]; jobs.j[2] = jobs.j[0]; jobs.j[3] = jobs.j[0];
    gemm_mfma<<<dim3(17, 8, 1), 256, 0, stream>>>(jobs, -1, nullptr, nullptr, nullptr, nullptr);
  }
}

// Round 13
// 288.873 us; speedup vs baseline: 1.6561x; 1.0406x over previous
//
#include <hip/hip_runtime.h>
#include <math.h>

// AdaptiveGraphAttention — MI355X, round 13.
// R12 measured: edge_scores 80us, MfmaUtil 1.5% (MFMA free — R11 theory wrong),
// VALUBusy 15%, Occ 31%: load-latency-serialized (~250cyc/load, no overlap).
// R13 (edge pipeline v4): (a) LN stats decomposed — sum/ss per P/Q row +
// PQdot (P_i . Q_j) precomputed in graph_prep; edge_scores becomes single-pass
// (half the loads, no stats dependency). (b) 2-wave channel split (256 ch per
// wave, LDS partial-acc combine): 8320 waves -> occupancy cap 101%.

constexpr int kD  = 512;
constexpr int kH  = 8;
constexpr int kHD = 64;
constexpr int kB  = 16;
constexpr int kN  = 64;
constexpr int kS  = 65;

typedef short bf16x8 __attribute__((ext_vector_type(8)));   // 8 bf16 bit-patterns
typedef float f32x4  __attribute__((ext_vector_type(4)));

__device__ __forceinline__ float wsum(float x) {
#pragma unroll
  for (int m = 1; m < 64; m <<= 1) x += __shfl_xor(x, m, 64);
  return x;
}
__device__ __forceinline__ float wmax(float x) {
#pragma unroll
  for (int m = 1; m < 64; m <<= 1) x = fmaxf(x, __shfl_xor(x, m, 64));
  return x;
}
__device__ __forceinline__ float osum(float x) {
  x += __shfl_xor(x, 8, 64);
  x += __shfl_xor(x, 16, 64);
  x += __shfl_xor(x, 32, 64);
  return x;
}

__device__ __forceinline__ unsigned short f2bf(float x) {   // RNE f32->bf16
  unsigned int u = __builtin_bit_cast(unsigned int, x);
  u += 0x7FFFu + ((u >> 16) & 1u);
  return (unsigned short)(u >> 16);
}
__device__ __forceinline__ float bf2f(unsigned short h) {
  return __builtin_bit_cast(float, ((unsigned int)h) << 16);
}
__device__ __forceinline__ unsigned int pk2(unsigned short a, unsigned short b) {
  return (unsigned int)a | ((unsigned int)b << 16);
}

// ---------------------------------------- weight transpose + bf16 hi/lo split
__global__ __launch_bounds__(256) void conv_w(
    const float* __restrict__ w_q, const float* __restrict__ w_k,
    const float* __restrict__ w_v, const float* __restrict__ w_e1,
    const float* __restrict__ w_o, const float* __restrict__ w_gt,
    unsigned short* __restrict__ wt)
{
  __shared__ float T[32][33];
  const int z = blockIdx.z;
  const float* src = (z == 0) ? w_q : (z == 1) ? w_k : (z == 2) ? w_v
                   : (z == 3) ? w_e1 : (z == 4) ? (w_e1 + 262144)
                   : (z == 5) ? w_o : w_gt;
  unsigned short* hi = wt + (size_t)z * 524288;
  unsigned short* lo = hi + 262144;
  const int n0 = blockIdx.x * 32, k0 = blockIdx.y * 32;
  const int tx = threadIdx.x & 31, ty0 = threadIdx.x >> 5;
#pragma unroll
  for (int it = 0; it < 4; ++it) {
    const int ky = ty0 + it * 8;
    T[ky][tx] = src[(size_t)(k0 + ky) * kD + n0 + tx];
  }
  __syncthreads();
#pragma unroll
  for (int it = 0; it < 4; ++it) {
    const int ny = ty0 + it * 8;
    const float x = T[tx][ny];              // = W[k0+tx][n0+ny]
    const unsigned short h = f2bf(x);
    hi[(size_t)(n0 + ny) * kD + k0 + tx] = h;
    lo[(size_t)(n0 + ny) * kD + k0 + tx] = f2bf(x - bf2f(h));
  }
}

// ----------------------------------------------- MFMA bf16-split GEMM (3-pass)
// [HW-validated R10/R12]
struct MJob { const float* A; const unsigned short* Wh; const unsigned short* Wl;
              const float* bias; float* C; int M; };
struct MJobs { MJob j[4]; };

__global__ __launch_bounds__(256) void gemm_mfma(
    MJobs jobs, int zNorms,
    const float* __restrict__ deN, const float* __restrict__ nvN,
    float* __restrict__ invde, float* __restrict__ invvar)
{
  if ((int)blockIdx.z == zNorms) {
    const int flat = blockIdx.x + gridDim.x * blockIdx.y;
    const int lane = threadIdx.x & 63;
    const int w = threadIdx.x >> 6;
#pragma unroll
    for (int r = 0; r < 4; ++r) {
      const int wid = flat * 16 + w * 4 + r;
      if (wid >= 2 * kB * kN) break;
      const float* row;
      if (wid < kB * kN) {
        row = deN + (size_t)wid * kD;
      } else {
        const int t = wid - kB * kN;
        row = nvN + ((size_t)(t / kN) * kS + 1 + (t % kN)) * kD;
      }
      const float4* r4 = reinterpret_cast<const float4*>(row) + lane * 2;
      const float4 x0 = r4[0], x1 = r4[1];
      float ss = x0.x * x0.x + x0.y * x0.y + x0.z * x0.z + x0.w * x0.w
               + x1.x * x1.x + x1.y * x1.y + x1.z * x1.z + x1.w * x1.w;
      ss = wsum(ss);
      if (lane == 0) {
        const float inv = 1.f / sqrtf(ss);
        if (wid < kB * kN) invde[wid] = inv; else invvar[wid - kB * kN] = inv;
      }
    }
    return;
  }

  const MJob jb = jobs.j[blockIdx.z];
  __shared__ unsigned short Ah[64][40], Al[64][40], Wh[64][40], Wl[64][40];
  const int tid = threadIdx.x;
  const int lane = tid & 63, wv = tid >> 6;
  const int wr = wv >> 1, wc = wv & 1;
  const int bm = blockIdx.x * 64, bn = blockIdx.y * 64;
  const int sr = tid >> 2, sk = (tid & 3) * 8;
  const bool aok = (bm + sr) < jb.M;
  const float* Ap = jb.A + (size_t)(bm + sr) * kD + sk;
  const unsigned short* Whp = jb.Wh + (size_t)(bn + sr) * kD + sk;
  const unsigned short* Wlp = jb.Wl + (size_t)(bn + sr) * kD + sk;

  const f32x4 zero = {0.f, 0.f, 0.f, 0.f};
  f32x4 acc00 = zero, acc01 = zero, acc10 = zero, acc11 = zero;

  for (int k0 = 0; k0 < kD; k0 += 32) {
    float4 a0 = {0.f, 0.f, 0.f, 0.f}, a1 = {0.f, 0.f, 0.f, 0.f};
    if (aok) {
      a0 = *reinterpret_cast<const float4*>(Ap + k0);
      a1 = *reinterpret_cast<const float4*>(Ap + k0 + 4);
    }
    const uint4 wh4 = *reinterpret_cast<const uint4*>(Whp + k0);
    const uint4 wl4 = *reinterpret_cast<const uint4*>(Wlp + k0);
    const float av[8] = {a0.x, a0.y, a0.z, a0.w, a1.x, a1.y, a1.z, a1.w};
    unsigned short h[8], l[8];
#pragma unroll
    for (int e = 0; e < 8; ++e) {
      h[e] = f2bf(av[e]);
      l[e] = f2bf(av[e] - bf2f(h[e]));
    }
    const uint4 hp = { pk2(h[0], h[1]), pk2(h[2], h[3]), pk2(h[4], h[5]), pk2(h[6], h[7]) };
    const uint4 lp = { pk2(l[0], l[1]), pk2(l[2], l[3]), pk2(l[4], l[5]), pk2(l[6], l[7]) };
    *reinterpret_cast<uint4*>(&Ah[sr][sk]) = hp;
    *reinterpret_cast<uint4*>(&Al[sr][sk]) = lp;
    *reinterpret_cast<uint4*>(&Wh[sr][sk]) = wh4;
    *reinterpret_cast<uint4*>(&Wl[sr][sk]) = wl4;
    __syncthreads();

    const int fr = lane & 15, kg = lane >> 4;
#pragma unroll
    for (int fm = 0; fm < 2; ++fm) {
      const int arow = wr * 32 + fm * 16 + fr;
      const bf16x8 amh = *reinterpret_cast<const bf16x8*>(&Ah[arow][kg * 8]);
      const bf16x8 aml = *reinterpret_cast<const bf16x8*>(&Al[arow][kg * 8]);
#pragma unroll
      for (int fn = 0; fn < 2; ++fn) {
        const int wrow = wc * 32 + fn * 16 + fr;
        const bf16x8 bh = *reinterpret_cast<const bf16x8*>(&Wh[wrow][kg * 8]);
        const bf16x8 bl = *reinterpret_cast<const bf16x8*>(&Wl[wrow][kg * 8]);
        f32x4 acc = (fm == 0) ? (fn == 0 ? acc00 : acc01) : (fn == 0 ? acc10 : acc11);
        acc = __builtin_amdgcn_mfma_f32_16x16x32_bf16(amh, bh, acc, 0, 0, 0);
        acc = __builtin_amdgcn_mfma_f32_16x16x32_bf16(amh, bl, acc, 0, 0, 0);
        acc = __builtin_amdgcn_mfma_f32_16x16x32_bf16(aml, bh, acc, 0, 0, 0);
        if (fm == 0) { if (fn == 0) acc00 = acc; else acc01 = acc; }
        else         { if (fn == 0) acc10 = acc; else acc11 = acc; }
      }
    }
    __syncthreads();
  }

  const int rg = lane >> 4, cc = lane & 15;
#pragma unroll
  for (int fm = 0; fm < 2; ++fm) {
#pragma unroll
    for (int fn = 0; fn < 2; ++fn) {
      const f32x4 acc = (fm == 0) ? (fn == 0 ? acc00 : acc01) : (fn == 0 ? acc10 : acc11);
      const int row0 = bm + wr * 32 + fm * 16 + rg * 4;
      const int col  = bn + wc * 32 + fn * 16 + cc;
      const float bb = jb.bias ? jb.bias[col] : 0.f;
#pragma unroll
      for (int e = 0; e < 4; ++e) {
        const int row = row0 + e;
        if (row < jb.M) jb.C[(size_t)row * kD + col] = acc[e] + bb;
      }
    }
  }
}

// --------------- fused: adjacency + qk + w2p prep + PQ row-stats + PQdot
// blocks: [0,1024) adjacency | [1024,1057) qk | [1057,1066) w2p
//         [1066,1194) P/Q row stats | [1194,2218) PQdot
__global__ __launch_bounds__(512) void graph_prep(
    const float* __restrict__ de, const float* __restrict__ nv,
    const float* __restrict__ invde, const float* __restrict__ invvar,
    const float* __restrict__ topo_p, float* __restrict__ adj,
    const float* __restrict__ q, const float* __restrict__ k,
    const float* __restrict__ w_attn,
    float* __restrict__ sq, float* __restrict__ sk,
    const float* __restrict__ w_edge2, const float* __restrict__ b_edge2,
    unsigned short* __restrict__ w2ph, unsigned short* __restrict__ w2pl,
    float* __restrict__ b2eff,
    const float* __restrict__ Pp, const float* __restrict__ Qq,
    float* __restrict__ s1p, float* __restrict__ s2p,
    float* __restrict__ s1q, float* __restrict__ s2q,
    float* __restrict__ pqd)
{
  const int blk = blockIdx.x;
  if (blk < kB * kN) {
    __shared__ float lg[kN];
    const int b = blk >> 6, i = blk & 63;
    const int w = threadIdx.x >> 6, lane = threadIdx.x & 63;
    const int p = lane & 7, oct = lane >> 3;
    const int j = w * 8 + p;
    const float topo = topo_p[0];
    const float4* di = reinterpret_cast<const float4*>(de + ((size_t)b * kN + i) * kD + oct * 64);
    const float4* dj = reinterpret_cast<const float4*>(de + ((size_t)b * kN + j) * kD + oct * 64);
    const float4* vi = reinterpret_cast<const float4*>(nv + ((size_t)b * kS + 1 + i) * kD + oct * 64);
    const float4* vj = reinterpret_cast<const float4*>(nv + ((size_t)b * kS + 1 + j) * kD + oct * 64);
    float g = 0.f, sv = 0.f;
#pragma unroll
    for (int t = 0; t < 16; ++t) {
      const float4 a = di[t], c = dj[t];
      g += a.x * c.x + a.y * c.y + a.z * c.z + a.w * c.w;
      const float4 x = vi[t], y = vj[t];
      sv += x.x * y.x + x.y * y.y + x.z * y.z + x.w * y.w;
    }
    g = osum(g);
    sv = osum(sv);
    if (oct == 0) {
      const float gs = g * invde[b * kN + i] * invde[b * kN + j] + topo;
      const bool hard = (gs > 0.f) && (j != i);   // sigmoid(x)>0.5 <=> x>0
      lg[j] = hard ? sv * invvar[b * kN + i] * invvar[b * kN + j] : 0.f;
    }
    __syncthreads();
    if (threadIdx.x < 64) {
      const float x = lg[lane];
      const float m = wmax(x);
      const float e = expf(x - m);
      const float s = wsum(e);
      adj[((size_t)b * kN + i) * kN + lane] = e / s;
    }
    return;
  }
  if (blk < kB * kN + 33) {
    const int t = (blk - kB * kN) * 512 + threadIdx.x;
    const int total = kB * kS * kH;
    if (t >= 2 * total) return;
    const int which = (t >= total) ? 1 : 0;
    const int r = which ? t - total : t;
    const int h = r % kH, bs = r / kH;
    const float* src = which ? k : q;
    const float* wa = w_attn + which * kHD;
    const float4* row = reinterpret_cast<const float4*>(src + (size_t)bs * kD + h * kHD);
    const float4* w4 = reinterpret_cast<const float4*>(wa);
    float acc = 0.f;
#pragma unroll
    for (int c = 0; c < kHD / 4; ++c) {
      const float4 a = row[c], w = w4[c];
      acc += a.x * w.x + a.y * w.y + a.z * w.z + a.w * w.w;
    }
    (which ? sk : sq)[r] = acc;
    return;
  }
  if (blk < kB * kN + 33 + 9) {
    const int rel = blk - (kB * kN + 33);     // 0..8
    const float4* wa4 = reinterpret_cast<const float4*>(w_attn + 2 * kHD);
    if (rel < 8) {
      const int t = rel * 512 + threadIdx.x;  // 0..4096
      const int c = t >> 3, h = t & 7;
      const float4* s4 = reinterpret_cast<const float4*>(w_edge2 + (size_t)c * kD + h * kHD);
      float acc = 0.f;
#pragma unroll
      for (int u = 0; u < kHD / 4; ++u) {
        const float4 a = s4[u], w = wa4[u];
        acc += a.x * w.x + a.y * w.y + a.z * w.z + a.w * w.w;
      }
      const unsigned short hi = f2bf(acc);
      w2ph[h * kD + c] = hi;
      w2pl[h * kD + c] = f2bf(acc - bf2f(hi));
    } else {
      if (threadIdx.x < kH) {
        const int h = threadIdx.x;
        float acc = 0.f;
        for (int d = 0; d < kHD; ++d)
          acc += b_edge2[h * kHD + d] * w_attn[2 * kHD + d];
        b2eff[h] = acc;
      }
      for (int u = threadIdx.x; u < 8 * kD; u += 512) {
        w2ph[8 * kD + u] = 0;
        w2pl[8 * kD + u] = 0;
      }
    }
    return;
  }
  if (blk < kB * kN + 33 + 9 + 128) {
    // ---- P/Q row stats: 128 blocks x (8 waves x 2 rows) = 2048 rows
    const int rel = blk - (kB * kN + 33 + 9);
    const int w = threadIdx.x >> 6, lane = threadIdx.x & 63;
#pragma unroll
    for (int pass = 0; pass < 2; ++pass) {
      const int rid = rel * 16 + w * 2 + pass;        // 0..2047
      const float* row = (rid < kB * kN) ? (Pp + (size_t)rid * kD)
                                         : (Qq + (size_t)(rid - kB * kN) * kD);
      const float4* r4 = reinterpret_cast<const float4*>(row) + lane * 2;
      const float4 x0 = r4[0], x1 = r4[1];
      float s = ((x0.x + x0.y) + (x0.z + x0.w)) + ((x1.x + x1.y) + (x1.z + x1.w));
      float ss = (x0.x * x0.x + x0.y * x0.y + x0.z * x0.z + x0.w * x0.w)
               + (x1.x * x1.x + x1.y * x1.y + x1.z * x1.z + x1.w * x1.w);
      s = wsum(s);
      ss = wsum(ss);
      if (lane == 0) {
        if (rid < kB * kN) { s1p[rid] = s; s2p[rid] = ss; }
        else               { s1q[rid - kB * kN] = s; s2q[rid - kB * kN] = ss; }
      }
    }
    return;
  }
  {
    // ---- PQdot: block per (b, ip): dot(P[b,ip], Q[b,j]) for j=0..63
    const int rel = blk - (kB * kN + 33 + 9 + 128);   // 0..1023
    const int b = rel >> 6, ip = rel & 63;
    const int w = threadIdx.x >> 6, lane = threadIdx.x & 63;
    const int p = lane & 7, oct = lane >> 3;
    const int j = w * 8 + p;
    const float4* Pr = reinterpret_cast<const float4*>(Pp + ((size_t)(b * kN + ip)) * kD + oct * 64);
    const float4* Qr = reinterpret_cast<const float4*>(Qq + ((size_t)(b * kN + j)) * kD + oct * 64);
    float d = 0.f;
#pragma unroll
    for (int t = 0; t < 16; ++t) {
      const float4 a = Pr[t], c = Qr[t];
      d += a.x * c.x + a.y * c.y + a.z * c.z + a.w * c.w;
    }
    d = osum(d);
    if (oct == 0)
      pqd[(size_t)(b * kN + ip) * kN + j] = d;
  }
}

// ------------------------------------------------------------ edge scores v4
// Single pass: LN stats from precomputed row sums/ss + PQdot. Block = 256 thr
// = 2 pair-groups x 2 channel-halves. Wave: 16 pairs x 256 channels; partial
// MFMA accs combined via LDS. A/B/C layouts = gemm_mfma [HW-validated].
__global__ __launch_bounds__(256) void edge_scores(
    const float* __restrict__ Pp, const float* __restrict__ Qq,
    const float* __restrict__ gamma, const float* __restrict__ beta,
    const unsigned short* __restrict__ w2ph, const unsigned short* __restrict__ w2pl,
    const float* __restrict__ b2eff,
    const float* __restrict__ s1p, const float* __restrict__ s2p,
    const float* __restrict__ s1q, const float* __restrict__ s2q,
    const float* __restrict__ pqd, float* __restrict__ es)
{
  __shared__ float sh[2][64][4];
  const int tid = threadIdx.x;
  const int wv = tid >> 6;
  const int pg = wv >> 1, half = wv & 1;
  const int lane = tid & 63;
  const int m = lane & 15, kg = lane >> 4;
  const int g = blockIdx.x * 2 + pg;                  // pair-group of 16
  const int base = g * 16;
  const int b = base / (kS * kN);
  const int r0 = base % (kS * kN);
  const int i = r0 / kN, j0 = r0 % kN;                // j0 multiple of 16
  const int jj = j0 + m;
  const int qrow = b * kN + jj;
  const int prow = (i == 0) ? qrow : (b * kN + i - 1);

  // LN stats from decomposition: z = P[prow] + Q[qrow]
  const float s1 = s1p[prow] + s1q[qrow];
  const float s2 = s2p[prow] + 2.f * pqd[(size_t)prow * kN + jj] + s2q[qrow];
  const float mu = s1 * (1.f / kD);
  const float var = s2 * (1.f / kD) - mu * mu;
  const float rstd = rsqrtf(var + 1e-5f);
  const float nb = -mu * rstd;

  const float* Pr = Pp + (size_t)prow * kD;
  const float* Qr = Qq + (size_t)qrow * kD;
  const int cbase = half * 256;

  const f32x4 zero = {0.f, 0.f, 0.f, 0.f};
  f32x4 accA = zero, accB = zero, accC = zero;
#pragma unroll
  for (int s = 0; s < 8; ++s) {
    const int c = cbase + s * 32 + kg * 8;
    const float4 pa = *reinterpret_cast<const float4*>(Pr + c);
    const float4 pb = *reinterpret_cast<const float4*>(Pr + c + 4);
    const float4 qa = *reinterpret_cast<const float4*>(Qr + c);
    const float4 qb = *reinterpret_cast<const float4*>(Qr + c + 4);
    const float4 ga = *reinterpret_cast<const float4*>(gamma + c);
    const float4 gb = *reinterpret_cast<const float4*>(gamma + c + 4);
    const float4 ba = *reinterpret_cast<const float4*>(beta + c);
    const float4 bb = *reinterpret_cast<const float4*>(beta + c + 4);
    const float zv[8] = { pa.x + qa.x, pa.y + qa.y, pa.z + qa.z, pa.w + qa.w,
                          pb.x + qb.x, pb.y + qb.y, pb.z + qb.z, pb.w + qb.w };
    const float gv[8] = { ga.x, ga.y, ga.z, ga.w, gb.x, gb.y, gb.z, gb.w };
    const float bv[8] = { ba.x, ba.y, ba.z, ba.w, bb.x, bb.y, bb.z, bb.w };
    unsigned short h8[8], l8[8];
#pragma unroll
    for (int e = 0; e < 8; ++e) {
      const float zn = fmaf(zv[e], rstd, nb);
      const float eu = fmaxf(fmaf(zn, gv[e], bv[e]), 0.f);
      h8[e] = f2bf(eu);
      l8[e] = f2bf(eu - bf2f(h8[e]));
    }
    const uint4 hp = { pk2(h8[0], h8[1]), pk2(h8[2], h8[3]), pk2(h8[4], h8[5]), pk2(h8[6], h8[7]) };
    const uint4 lp = { pk2(l8[0], l8[1]), pk2(l8[2], l8[3]), pk2(l8[4], l8[5]), pk2(l8[6], l8[7]) };
    const bf16x8 Af_h = __builtin_bit_cast(bf16x8, hp);
    const bf16x8 Af_l = __builtin_bit_cast(bf16x8, lp);
    const bf16x8 Bh = *reinterpret_cast<const bf16x8*>(w2ph + (size_t)m * kD + c);
    const bf16x8 Bl = *reinterpret_cast<const bf16x8*>(w2pl + (size_t)m * kD + c);
    accA = __builtin_amdgcn_mfma_f32_16x16x32_bf16(Af_h, Bh, accA, 0, 0, 0);
    accB = __builtin_amdgcn_mfma_f32_16x16x32_bf16(Af_h, Bl, accB, 0, 0, 0);
    accC = __builtin_amdgcn_mfma_f32_16x16x32_bf16(Af_l, Bh, accC, 0, 0, 0);
  }

  float acc[4];
#pragma unroll
  for (int e = 0; e < 4; ++e) acc[e] = (accA[e] + accB[e]) + accC[e];

  if (half == 1) {
#pragma unroll
    for (int e = 0; e < 4; ++e) sh[pg][lane][e] = acc[e];
  }
  __syncthreads();
  if (half == 0) {
    const int n = lane & 15;
    if (n < kH) {
      const float be = b2eff[n];
#pragma unroll
      for (int e = 0; e < 4; ++e) {
        const int mp = kg * 4 + e;
        es[(((size_t)b * kS + i) * kS + (j0 + mp + 1)) * kH + n]
            = acc[e] + sh[pg][lane][e] + be;
      }
    }
  }
}

// --------------------------------------------- attn softmax + context rows
__global__ __launch_bounds__(576) void attn_ctx(
    const float* __restrict__ sq, const float* __restrict__ sk,
    const float* __restrict__ es, const float* __restrict__ adj,
    const float* __restrict__ v, const float* __restrict__ b_attn,
    float* __restrict__ attn_out, float* __restrict__ ctx)
{
  __shared__ float prob[kH][kS];
  const int bi = blockIdx.x;
  const int b = bi / kS, i = bi % kS;
  const int tid = threadIdx.x;
  const float ba = b_attn[0];
  if (tid < kH * kS) {
    const int h = tid / kS, j = tid % kS;
    float lgv;
    if (j == 0) {
      lgv = -1e30f;
    } else {
      const float a = (i == 0) ? 1.f : adj[((size_t)b * kN + (i - 1)) * kN + (j - 1)];
      lgv = sq[(b * kS + i) * kH + h] + sk[(b * kS + j) * kH + h]
          + es[(((size_t)b * kS + i) * kS + j) * kH + h] * a + ba;
    }
    prob[h][j] = lgv;
  }
  __syncthreads();
  const int w = tid >> 6, lane = tid & 63;
  if (w < kH) {
    const float x = prob[w][lane];
    const float xe = prob[w][64];
    float m = wmax(x);
    m = fmaxf(m, xe);
    const float e = expf(x - m);
    const float ee = expf(xe - m);
    const float s = wsum(e) + ee;
    const float inv = 1.f / s;
    prob[w][lane] = e * inv;
    if (lane == 0) prob[w][64] = ee * inv;
  }
  __syncthreads();
  if (tid < kH * kS) {
    const int h = tid / kS, j = tid % kS;
    attn_out[(((size_t)b * kH + h) * kS + i) * kS + j] = prob[h][j];
  }
  if (tid < kD) {
    const int h = tid >> 6, d = tid & 63;
    const float* vb = v + (size_t)b * kS * kD + h * kHD + d;
    float a0 = 0.f, a1 = 0.f, a2 = 0.f, a3 = 0.f;
#pragma unroll 4
    for (int j = 1; j < kS; j += 4) {
      a0 = fmaf(prob[h][j + 0], vb[(size_t)(j + 0) * kD], a0);
      a1 = fmaf(prob[h][j + 1], vb[(size_t)(j + 1) * kD], a1);
      a2 = fmaf(prob[h][j + 2], vb[(size_t)(j + 2) * kD], a2);
      a3 = fmaf(prob[h][j + 3], vb[(size_t)(j + 3) * kD], a3);
    }
    ctx[((size_t)b * kS + i) * kD + tid] = (a0 + a1) + (a2 + a3);
  }
}

// ---------------------------------------------------------------- launcher
extern "C" void kernel_launch(void* const* d_in, const int* in_sizes, int n_in,
                              void* d_out, int out_size, void* d_ws, size_t ws_size,
                              hipStream_t stream)
{
  const float* desc = (const float*)d_in[0];
  const float* nv   = (const float*)d_in[1];
  const float* w_gt = (const float*)d_in[2];
  const float* b_gt = (const float*)d_in[3];
  const float* topo = (const float*)d_in[4];
  const float* w_e1 = (const float*)d_in[5];
  const float* b_e1 = (const float*)d_in[6];
  const float* ln_g = (const float*)d_in[7];
  const float* ln_b = (const float*)d_in[8];
  const float* w_e2 = (const float*)d_in[9];
  const float* b_e2 = (const float*)d_in[10];
  const float* w_q  = (const float*)d_in[11];
  const float* b_q  = (const float*)d_in[12];
  const float* w_k  = (const float*)d_in[13];
  const float* b_k  = (const float*)d_in[14];
  const float* w_v  = (const float*)d_in[15];
  const float* b_v  = (const float*)d_in[16];
  const float* w_at = (const float*)d_in[17];
  const float* b_at = (const float*)d_in[18];
  const float* w_o  = (const float*)d_in[19];
  const float* b_o  = (const float*)d_in[20];

  float* ws  = (float*)d_ws;
  float* de  = ws;                    // B*N*D
  float* q   = de  + 524288;          // B*S*D
  float* k   = q   + 532480;
  float* v   = k   + 532480;
  float* Pp  = v   + 532480;          // B*N*D
  float* Qq  = Pp  + 524288;
  float* adj = Qq  + 524288;          // B*N*N
  float* sq  = adj + 65536;           // B*S*H
  float* sk  = sq  + 8320;
  float* es  = sk  + 8320;            // B*S*S*H
  float* ctx = es  + 540800;          // B*S*D
  float* b2e = ctx + 532480;          // H (+pad)
  float* ivd = b2e + 8;               // B*N
  float* ivv = ivd + 1024;            // B*N
  float* s1p = ivv + 1024;            // B*N
  float* s2p = s1p + 1024;
  float* s1q = s2p + 1024;
  float* s2q = s1q + 1024;
  float* pqd = s2q + 1024;            // B*N*N = 65536
  unsigned short* wt   = (unsigned short*)(pqd + 65536); // 7 x (hi 256K + lo 256K)
  unsigned short* w2ph = wt + 7u * 524288;               // 16 x 512 bf16 (padded)
  unsigned short* w2pl = w2ph + 8192;

  float* out  = (float*)d_out;                 // (B,S,D)
  float* attn = out + (size_t)kB * kS * kD;    // (B,H,S,S)

  // D0: weight transpose + bf16 hi/lo conversion (wq,wk,wv,we1a,we1b,wo,wgt)
  conv_w<<<dim3(16, 16, 7), 256, 0, stream>>>(w_q, w_k, w_v, w_e1, w_o, w_gt, wt);
  // D1: de,q,k,v via MFMA bf16-split
  {
    MJobs jobs;
    jobs.j[0] = { desc, wt + 6u * 524288, wt + 6u * 524288 + 262144, b_gt, de, kB * kN };
    jobs.j[1] = { nv,   wt + 0u * 524288, wt + 0u * 524288 + 262144, b_q,  q,  kB * kS };
    jobs.j[2] = { nv,   wt + 1u * 524288, wt + 1u * 524288 + 262144, b_k,  k,  kB * kS };
    jobs.j[3] = { nv,   wt + 2u * 524288, wt + 2u * 524288 + 262144, b_v,  v,  kB * kS };
    gemm_mfma<<<dim3(17, 8, 4), 256, 0, stream>>>(jobs, -1, nullptr, nullptr, nullptr, nullptr);
  }
  // D2: P,Q via MFMA + norms as z=2 slice
  {
    MJobs jobs;
    jobs.j[0] = { de, wt + 3u * 524288, wt + 3u * 524288 + 262144, b_e1,   Pp, kB * kN };
    jobs.j[1] = { de, wt + 4u * 524288, wt + 4u * 524288 + 262144, nullptr, Qq, kB * kN };
    jobs.j[2] = jobs.j[0]; jobs.j[3] = jobs.j[0];
    gemm_mfma<<<dim3(16, 8, 3), 256, 0, stream>>>(jobs, 2, de, nv, ivd, ivv);
  }
  // D3: adjacency (1024) + qk (33) + w2p (9) + P/Q row stats (128) + PQdot (1024)
  graph_prep<<<2218, 512, 0, stream>>>(de, nv, ivd, ivv, topo, adj,
                                       q, k, w_at, sq, sk,
                                       w_e2, b_e2, w2ph, w2pl, b2e,
                                       Pp, Qq, s1p, s2p, s1q, s2q, pqd);
  // D4: edge scores v4: 4160 pair-groups / 2 per block
  edge_scores<<<2080, 256, 0, stream>>>(Pp, Qq, ln_g, ln_b, w2ph, w2pl, b2e,
                                        s1p, s2p, s1q, s2q, pqd, es);
  // D5: attention softmax + context
  attn_ctx<<<kB * kS, 576, 0, stream>>>(sq, sk, es, adj, v, b_at, attn, ctx);
  // D6: output projection via MFMA
  {
    MJobs jobs;
    jobs.j[0] = { ctx, wt + 5u * 524288, wt + 5u * 524288 + 262144, b_o, out, kB * kS };
    jobs.j[1] = jobs.j[0]; jobs.j[2] = jobs.j[0]; jobs.j[3] = jobs.j[0];
    gemm_mfma<<<dim3(17, 8, 1), 256, 0, stream>>>(jobs, -1, nullptr, nullptr, nullptr, nullptr);
  }
}